// Round 4
// baseline (496.375 us; speedup 1.0000x reference)
//
#include <hip/hip_runtime.h>
#include <stdint.h>

// SparseMoE: B=4,S=2048,D=1024,E=8,H=2048, top-k=2.
// Outputs (concat, float32): final_output[8192*1024], top_k_indices[8192*2] (as floats), aux_loss[1].

#define NTOK   8192
#define DIM    1024
#define NEXP   8
#define HID    2048
#define OUT_MAIN (NTOK * DIM)          // 8388608
#define IDX_OFF  OUT_MAIN
#define AUX_OFF  (OUT_MAIN + NTOK * 2) // 8404992
#define MAXBLK 72                      // >= 64 + 7 worst-case 256-row m-blocks over 8 experts

typedef __attribute__((ext_vector_type(8))) short short8;
typedef __attribute__((ext_vector_type(4))) float floatx4;

__device__ __forceinline__ unsigned short f2bf(float f) {
  unsigned int b = __float_as_uint(f);
  b += 0x7FFFu + ((b >> 16) & 1u);      // RNE; inputs finite
  return (unsigned short)(b >> 16);
}

// ---------------- gating: logits (fp64 acc), top-2, masked softmax, scatter, xb=bf16(x) ---
__global__ __launch_bounds__(1024) void k_gating(
    const float* __restrict__ x, const float* __restrict__ gate_w,
    const float* __restrict__ gate_b, const float* __restrict__ noise,
    float* __restrict__ out, int* __restrict__ counts,
    int* __restrict__ lists_tok, float* __restrict__ lists_p,
    float* __restrict__ probs_all, unsigned short* __restrict__ xb)
{
  const int lane = threadIdx.x & 63;
  const int wv   = threadIdx.x >> 6;              // 0..15
  const int t    = blockIdx.x * 16 + wv;          // one token per wave
  const float* xr = x + (size_t)t * DIM;

  __shared__ int   cnt[NEXP];
  __shared__ int   base[NEXP];
  __shared__ int   s_e[32];
  __shared__ int   s_pos[32];
  __shared__ float s_p[32];
  if (threadIdx.x < NEXP) cnt[threadIdx.x] = 0;

  double acc[NEXP] = {0,0,0,0,0,0,0,0};
  #pragma unroll
  for (int jj = 0; jj < 4; ++jj) {
    const int d0 = lane * 4 + jj * 256;
    const float4 xv = *(const float4*)(xr + d0);
    const float xs[4] = {xv.x, xv.y, xv.z, xv.w};
    unsigned short xbq[4];
    #pragma unroll
    for (int c = 0; c < 4; ++c) {
      const float4 g0 = *(const float4*)(gate_w + (size_t)(d0 + c) * NEXP);
      const float4 g1 = *(const float4*)(gate_w + (size_t)(d0 + c) * NEXP + 4);
      const double xd = (double)xs[c];
      acc[0] += xd * (double)g0.x; acc[1] += xd * (double)g0.y;
      acc[2] += xd * (double)g0.z; acc[3] += xd * (double)g0.w;
      acc[4] += xd * (double)g1.x; acc[5] += xd * (double)g1.y;
      acc[6] += xd * (double)g1.z; acc[7] += xd * (double)g1.w;
      xbq[c] = f2bf(xs[c]);
    }
    ushort4 q; q.x = xbq[0]; q.y = xbq[1]; q.z = xbq[2]; q.w = xbq[3];
    *(ushort4*)(xb + (size_t)t * DIM + d0) = q;
  }
  #pragma unroll
  for (int e = 0; e < NEXP; ++e) {
    #pragma unroll
    for (int off = 32; off; off >>= 1) acc[e] += __shfl_xor(acc[e], off);
  }
  __syncthreads();                                 // cnt[] initialized
  if (lane == 0) {
    double l[NEXP];
    #pragma unroll
    for (int e = 0; e < NEXP; ++e)
      l[e] = acc[e] + (double)gate_b[e] + 0.01 * (double)noise[(size_t)t * NEXP + e];
    int i1 = 0; double v1 = l[0];
    #pragma unroll
    for (int e = 1; e < NEXP; ++e) if (l[e] > v1) { v1 = l[e]; i1 = e; }
    int i2 = (i1 == 0) ? 1 : 0; double v2 = l[i2];
    #pragma unroll
    for (int e = 0; e < NEXP; ++e) if (e != i1 && l[e] > v2) { v2 = l[e]; i2 = e; }
    float pr[NEXP]; float Z = 0.f;
    #pragma unroll
    for (int e = 0; e < NEXP; ++e) {
      const float a = (l[e] >= v2) ? (float)(l[e] - v1) : -1.0e9f;
      pr[e] = __expf(a); Z += pr[e];
    }
    const float rz = 1.0f / Z;
    #pragma unroll
    for (int e = 0; e < NEXP; ++e) {
      pr[e] *= rz;
      probs_all[(size_t)t * NEXP + e] = pr[e];
    }
    out[(size_t)IDX_OFF + t * 2]     = (float)i1;
    out[(size_t)IDX_OFF + t * 2 + 1] = (float)i2;
    const int p1 = atomicAdd(&cnt[i1], 1);
    const int p2 = atomicAdd(&cnt[i2], 1);
    s_e[wv * 2]     = i1; s_pos[wv * 2]     = p1; s_p[wv * 2]     = pr[i1];
    s_e[wv * 2 + 1] = i2; s_pos[wv * 2 + 1] = p2; s_p[wv * 2 + 1] = pr[i2];
  }
  __syncthreads();
  if (threadIdx.x < NEXP) base[threadIdx.x] = atomicAdd(&counts[threadIdx.x], cnt[threadIdx.x]);
  __syncthreads();
  if (lane == 0) {
    #pragma unroll
    for (int k = 0; k < 2; ++k) {
      const int ee  = s_e[wv * 2 + k];
      const int pos = base[ee] + s_pos[wv * 2 + k];
      lists_tok[ee * NTOK + pos] = t;
      lists_p[ee * NTOK + pos]   = s_p[wv * 2 + k];
    }
  }
}

// ---------------- offsets + balanced XCD-local block table (256-row m-granularity) -----
// HW assigns XCD = linear_block_id % 8; gridDim.x=72 (≡0 mod 8) -> XCD = bx%8 for all by.
// XCD class c = pos%8 gets a CONTIGUOUS run of valid entries (expert/B-slice L2 locality)
// partitioned balanced over the VALID count. Invalid slots = -1.
__global__ void k_offs(const int* __restrict__ counts, int* __restrict__ offs,
                       int* __restrict__ tbl_e, int* __restrict__ tbl_m,
                       int* __restrict__ nblk) {
  if (threadIdx.x == 0) {
    int a = 0;
    #pragma unroll
    for (int e = 0; e < NEXP; ++e) { offs[e] = a; a += counts[e]; }
    offs[NEXP] = a;
    int ent_e[MAXBLK], ent_m[MAXBLK];
    int nb = 0;
    for (int e = 0; e < NEXP; ++e) {
      const int nbe = (counts[e] + 255) >> 8;
      for (int m = 0; m < nbe; ++m) { ent_e[nb] = e; ent_m[nb] = m << 8; ++nb; }
    }
    nblk[0] = nb;
    for (int p = 0; p < MAXBLK; ++p) { tbl_e[p] = -1; tbl_m[p] = 0; }
    const int q = nb >> 3, r = nb & 7;
    for (int c = 0; c < 8; ++c) {
      const int cnt   = q + (c < r ? 1 : 0);          // <= 9
      const int start = c * q + (c < r ? c : r);
      for (int t = 0; t < cnt; ++t) {
        const int pos = c + (t << 3);                 // pos%8 == c, pos < 72
        tbl_e[pos] = ent_e[start + t];
        tbl_m[pos] = ent_m[start + t];
      }
    }
  }
}

// ---------------- aux loss ----------------
__global__ __launch_bounds__(256) void k_aux(const float* __restrict__ probs_all,
                                             float* __restrict__ out) {
  float p[NEXP] = {0,0,0,0,0,0,0,0};
  for (int t = threadIdx.x; t < NTOK; t += 256) {
    const float4 a = *(const float4*)(probs_all + (size_t)t * NEXP);
    const float4 b = *(const float4*)(probs_all + (size_t)t * NEXP + 4);
    p[0] += a.x; p[1] += a.y; p[2] += a.z; p[3] += a.w;
    p[4] += b.x; p[5] += b.y; p[6] += b.z; p[7] += b.w;
  }
  #pragma unroll
  for (int e = 0; e < NEXP; ++e) {
    #pragma unroll
    for (int off = 32; off; off >>= 1) p[e] += __shfl_xor(p[e], off);
  }
  __shared__ float red[4][NEXP];
  const int lane = threadIdx.x & 63, wv = threadIdx.x >> 6;
  if (lane == 0) {
    #pragma unroll
    for (int e = 0; e < NEXP; ++e) red[wv][e] = p[e];
  }
  __syncthreads();
  if (threadIdx.x == 0) {
    float usage[NEXP], s = 0.f;
    #pragma unroll
    for (int e = 0; e < NEXP; ++e) {
      usage[e] = red[0][e] + red[1][e] + red[2][e] + red[3][e];
      s += usage[e];
    }
    float imp[NEXP], mean = 0.f, var = 0.f;
    #pragma unroll
    for (int e = 0; e < NEXP; ++e) { imp[e] = usage[e] / s; mean += imp[e]; }
    mean *= 0.125f;
    #pragma unroll
    for (int e = 0; e < NEXP; ++e) { const float d = imp[e] - mean; var += d * d; }
    var *= 0.125f;
    out[AUX_OFF] = sqrtf(var) / (mean + 1e-10f);
  }
}

// ---------------- weight transpose+convert: in[e][r][c] fp32 -> out[e][c-c0][r-r0] bf16 ---
__global__ __launch_bounds__(256) void k_tr(
    const float* __restrict__ in, unsigned short* __restrict__ out,
    int in_ld, size_t in_estride, int r0, int c0,
    int out_ld, size_t out_estride)
{
  const int e  = blockIdx.z;
  const int tr = blockIdx.x << 6;
  const int tc = blockIdx.y << 6;
  const int tid = threadIdx.x;
  __shared__ float t[64][65];
  const float* src = in + (size_t)e * in_estride + (size_t)(r0 + tr) * in_ld + (c0 + tc);
  #pragma unroll
  for (int p = 0; p < 4; ++p) {
    const int r  = (p << 4) + (tid >> 4);
    const int c4 = (tid & 15) << 2;
    const float4 v = *(const float4*)(src + (size_t)r * in_ld + c4);
    t[r][c4] = v.x; t[r][c4 + 1] = v.y; t[r][c4 + 2] = v.z; t[r][c4 + 3] = v.w;
  }
  __syncthreads();
  unsigned short* dst = out + (size_t)e * out_estride + (size_t)tc * out_ld + tr;
  #pragma unroll
  for (int p = 0; p < 4; ++p) {
    const int c  = (p << 4) + (tid >> 4);
    const int r4 = (tid & 15) << 2;
    ushort4 q;
    q.x = f2bf(t[r4][c]);     q.y = f2bf(t[r4 + 1][c]);
    q.z = f2bf(t[r4 + 2][c]); q.w = f2bf(t[r4 + 3][c]);
    *(ushort4*)(dst + (size_t)c * out_ld + r4) = q;
  }
}

// ---------------- grouped MFMA GEMM: 256x256 tile, 8 waves, BK=64, 4-phase interleave ---
// Fine-interleaved phase schedule (T1..T5 full stack, m248 regime):
//   8 waves 2Mx4N, per-wave 128x64 out (acc[8][4]); LDS 2x(A,B)x[256][64] = 128 KB.
//   Per K-tile u (buf p=u&1), 4 phases, quadrant order (mLo,nLo)(mLo,nHi)(mHi,nHi)(mHi,nLo);
//   A-frags / B-nHi frags held in regs across adjacent phases.
//   One region staged per phase into the region freed by the previous phase's trailing
//   barrier (regions: A-mh0, B-n1, A-mh1, B-n0 of the OTHER-use tile):
//     u.ph0: B-n0(u+1)->buf p^1   u.ph1: A-mh0(u+2)->buf p
//     u.ph2: B-n1(u+2)->buf p     u.ph3: A-mh1(u+2)->buf p
//   vmcnt(8) once per K-tile at ph0 (8 = 4 younger piece-events x 2 calls); vmcnt(0)
//   only on the last tile. setprio around each 16-MFMA cluster; sched_barrier(0) fences.
// MODE 0: h[slot, nb+n] = silu( xb[tok] @ w1t[e][nb+n][:] + b1 )   (Kloc = 1024)
// MODE 1 (no split-K): out[tok, nb+n] += p * ( h[slot] @ w2t[e][nb+n][:] + b2 ) (Kloc = Hs)
// LDS [row][64] 16B-chunk XOR swizzle (r3-verified, conflicts=0): LDS[r][j]=glob[r][j^(r&7)].
template <int MODE>
__global__ __launch_bounds__(512, 2) void k_gemm(
    const unsigned short* __restrict__ Abase,
    const unsigned short* __restrict__ Bt,
    const float* __restrict__ bias,
    const int* __restrict__ counts, const int* __restrict__ offs,
    const int* __restrict__ tbl_e, const int* __restrict__ tbl_m,
    const int* __restrict__ nblk,
    const int* __restrict__ lists_tok, const float* __restrict__ lists_p,
    unsigned short* __restrict__ hout, float* __restrict__ out,
    const int hb, const int Hs)
{
  const int bx = blockIdx.x;
  const int e  = tbl_e[bx];
  if (e < 0) return;
  const int m0  = tbl_m[bx];
  const int n_e = counts[e];
  const int nb  = blockIdx.y << 8;

  const int Kloc = (MODE == 0) ? DIM : Hs;   // K extent == row stride of A and B
  const int nt   = Kloc >> 6;

  const int tid  = threadIdx.x;
  const int lane = tid & 63;
  const int wv   = tid >> 6;                 // 0..7
  const int wm   = (wv & 1) << 7;            // 0 / 128
  const int wn   = (wv >> 1) << 6;           // 0 / 64 / 128 / 192

  __shared__ __align__(16) unsigned short as[2][256 * 64];  // 2 x 32 KB
  __shared__ __align__(16) unsigned short bs[2][256 * 64];  // 2 x 32 KB
  unsigned short* const A0 = &as[0][0]; unsigned short* const A1 = &as[1][0];
  unsigned short* const B0 = &bs[0][0]; unsigned short* const B1 = &bs[1][0];

  const unsigned short* Bexp = Bt + (size_t)e * ((size_t)DIM * Hs) + (size_t)nb * Kloc;

  // staging geometry: each gload_lds call = 8 consecutive rows x 64 cols (1 KB).
  // lane l covers row grp+(l>>3), chunk l&7; source chunk (l&7)^(l>>3) -> swizzled LDS.
  const int off_sh = ((lane & 7) ^ (lane >> 3)) << 3;   // shorts
  const int r0  = (wv << 3) + (lane >> 3);                               // 0..63
  const int rb0 = ((wv >> 2) << 6) + ((wv & 3) << 3) + (lane >> 3);      // {0..31}u{64..95}
  // A source pointers, m-quarters 0..3 (rows r0 + 64q)
  const unsigned short* pA0; const unsigned short* pA1;
  const unsigned short* pA2; const unsigned short* pA3;
  {
    const unsigned short* p[4];
    #pragma unroll
    for (int qq = 0; qq < 4; ++qq) {
      const int rr = m0 + r0 + (qq << 6);
      const int rc = (rr < n_e) ? rr : (n_e - 1);
      size_t arow;
      if (MODE == 0) arow = (size_t)lists_tok[e * NTOK + rc] * DIM;
      else           arow = (size_t)(offs[e] + rc) * Hs;
      p[qq] = Abase + arow + off_sh;
    }
    pA0 = p[0]; pA1 = p[1]; pA2 = p[2]; pA3 = p[3];
  }
  // B source pointers: n0 region rows {rb0, rb0+128}, n1 region rows {rb0+32, rb0+160}
  const unsigned short* pB0 = Bexp + (size_t)rb0 * Kloc + off_sh;
  const unsigned short* pB1 = Bexp + (size_t)(rb0 + 32) * Kloc + off_sh;
  const unsigned short* pB2 = Bexp + (size_t)(rb0 + 128) * Kloc + off_sh;
  const unsigned short* pB3 = Bexp + (size_t)(rb0 + 160) * Kloc + off_sh;
  // LDS dest bases (shorts)
  const int dA = (wv << 3) * 64;                               // A group (row wv*8)
  const int dB = (((wv >> 2) << 6) + ((wv & 3) << 3)) * 64;    // B group

  auto ST = [&](const unsigned short* g, unsigned short* l) {
    __builtin_amdgcn_global_load_lds(
        (const __attribute__((address_space(1))) void*)g,
        (__attribute__((address_space(3))) void*)(void*)l, 16, 0, 0);
  };
  // stage events: 2 calls each, tile-guarded
  auto STG_A0 = [&](unsigned short* ab, int t) { if (t < nt) { const int kk = t << 6;
      ST(pA0 + kk, ab + dA); ST(pA2 + kk, ab + 2 * 4096 + dA); } };
  auto STG_A1 = [&](unsigned short* ab, int t) { if (t < nt) { const int kk = t << 6;
      ST(pA1 + kk, ab + 4096 + dA); ST(pA3 + kk, ab + 3 * 4096 + dA); } };
  auto STG_B0 = [&](unsigned short* bb, int t) { if (t < nt) { const int kk = t << 6;
      ST(pB0 + kk, bb + dB); ST(pB2 + kk, bb + 8192 + dB); } };
  auto STG_B1 = [&](unsigned short* bb, int t) { if (t < nt) { const int kk = t << 6;
      ST(pB1 + kk, bb + 2048 + dB); ST(pB3 + kk, bb + 10240 + dB); } };

  auto LDA8 = [&](const unsigned short* ab, int i, int s) -> short8 {
    const int row = wm + (i << 4) + (lane & 15);
    const int ck  = (((s << 2) | (lane >> 4)) ^ (row & 7)) << 3;
    return *(const short8*)(ab + row * 64 + ck);
  };
  auto LDB8 = [&](const unsigned short* bb, int j, int s) -> short8 {
    const int row = wn + (j << 4) + (lane & 15);
    const int ck  = (((s << 2) | (lane >> 4)) ^ (row & 7)) << 3;
    return *(const short8*)(bb + row * 64 + ck);
  };

  floatx4 acc[8][4];
  #pragma unroll
  for (int i = 0; i < 8; ++i)
    #pragma unroll
    for (int j = 0; j < 4; ++j) acc[i][j] = (floatx4){0.f, 0.f, 0.f, 0.f};

  // prologue: pieces in steady-state program order
  STG_A0(A0, 0); STG_B1(B0, 0); STG_A1(A0, 0); STG_B0(B0, 0);
  STG_A0(A1, 1); STG_B1(B1, 1); STG_A1(A1, 1);

  short8 a_[4][2], b_[2][2];
  for (int u = 0; u < nt; ++u) {
    const int p = u & 1;
    const unsigned short* ap = p ? A1 : A0;
    const unsigned short* bp = p ? B1 : B0;
    unsigned short* apn = p ? A0 : A1;   // other buf (holds tile u+1); staging tgt u.ph0
    unsigned short* apc = p ? A1 : A0;   // current buf; staging tgt tile u+2
    unsigned short* bpn = p ? B0 : B1;
    unsigned short* bpc = p ? B1 : B0;
    (void)apn;

    // ---- ph0: (mLo, nLo) ----
    STG_B0(bpn, u + 1);
    if (u + 1 < nt) { asm volatile("s_waitcnt vmcnt(8)" ::: "memory"); }
    else            { asm volatile("s_waitcnt vmcnt(0)" ::: "memory"); }
    __builtin_amdgcn_sched_barrier(0);
    __builtin_amdgcn_s_barrier();
    __builtin_amdgcn_sched_barrier(0);
    #pragma unroll
    for (int i = 0; i < 4; ++i) { a_[i][0] = LDA8(ap, i, 0); a_[i][1] = LDA8(ap, i, 1); }
    #pragma unroll
    for (int j = 0; j < 2; ++j) { b_[j][0] = LDB8(bp, j, 0); b_[j][1] = LDB8(bp, j, 1); }
    asm volatile("s_waitcnt lgkmcnt(0)" ::: "memory");
    __builtin_amdgcn_sched_barrier(0);
    __builtin_amdgcn_s_setprio(1);
    #pragma unroll
    for (int s = 0; s < 2; ++s)
      #pragma unroll
      for (int i = 0; i < 4; ++i)
        #pragma unroll
        for (int j = 0; j < 2; ++j)
          acc[i][j] = __builtin_amdgcn_mfma_f32_16x16x32_bf16(a_[i][s], b_[j][s], acc[i][j], 0, 0, 0);
    __builtin_amdgcn_s_setprio(0);
    __builtin_amdgcn_sched_barrier(0);
    __builtin_amdgcn_s_barrier();
    __builtin_amdgcn_sched_barrier(0);

    // ---- ph1: (mLo, nHi) — reuse a_, read B-n1 ----
    STG_A0(apc, u + 2);
    #pragma unroll
    for (int j = 0; j < 2; ++j) { b_[j][0] = LDB8(bp, j + 2, 0); b_[j][1] = LDB8(bp, j + 2, 1); }
    __builtin_amdgcn_sched_barrier(0);
    __builtin_amdgcn_s_barrier();
    __builtin_amdgcn_sched_barrier(0);
    asm volatile("s_waitcnt lgkmcnt(0)" ::: "memory");
    __builtin_amdgcn_sched_barrier(0);
    __builtin_amdgcn_s_setprio(1);
    #pragma unroll
    for (int s = 0; s < 2; ++s)
      #pragma unroll
      for (int i = 0; i < 4; ++i)
        #pragma unroll
        for (int j = 0; j < 2; ++j)
          acc[i][j + 2] = __builtin_amdgcn_mfma_f32_16x16x32_bf16(a_[i][s], b_[j][s], acc[i][j + 2], 0, 0, 0);
    __builtin_amdgcn_s_setprio(0);
    __builtin_amdgcn_sched_barrier(0);
    __builtin_amdgcn_s_barrier();
    __builtin_amdgcn_sched_barrier(0);

    // ---- ph2: (mHi, nHi) — reuse b_, read A-mh1 ----
    STG_B1(bpc, u + 2);
    #pragma unroll
    for (int i = 0; i < 4; ++i) { a_[i][0] = LDA8(ap, i + 4, 0); a_[i][1] = LDA8(ap, i + 4, 1); }
    __builtin_amdgcn_sched_barrier(0);
    __builtin_amdgcn_s_barrier();
    __builtin_amdgcn_sched_barrier(0);
    asm volatile("s_waitcnt lgkmcnt(0)" ::: "memory");
    __builtin_amdgcn_sched_barrier(0);
    __builtin_amdgcn_s_setprio(1);
    #pragma unroll
    for (int s = 0; s < 2; ++s)
      #pragma unroll
      for (int i = 0; i < 4; ++i)
        #pragma unroll
        for (int j = 0; j < 2; ++j)
          acc[i + 4][j + 2] = __builtin_amdgcn_mfma_f32_16x16x32_bf16(a_[i][s], b_[j][s], acc[i + 4][j + 2], 0, 0, 0);
    __builtin_amdgcn_s_setprio(0);
    __builtin_amdgcn_sched_barrier(0);
    __builtin_amdgcn_s_barrier();
    __builtin_amdgcn_sched_barrier(0);

    // ---- ph3: (mHi, nLo) — reuse a_, re-read B-n0 ----
    STG_A1(apc, u + 2);
    #pragma unroll
    for (int j = 0; j < 2; ++j) { b_[j][0] = LDB8(bp, j, 0); b_[j][1] = LDB8(bp, j, 1); }
    __builtin_amdgcn_sched_barrier(0);
    __builtin_amdgcn_s_barrier();
    __builtin_amdgcn_sched_barrier(0);
    asm volatile("s_waitcnt lgkmcnt(0)" ::: "memory");
    __builtin_amdgcn_sched_barrier(0);
    __builtin_amdgcn_s_setprio(1);
    #pragma unroll
    for (int s = 0; s < 2; ++s)
      #pragma unroll
      for (int i = 0; i < 4; ++i)
        #pragma unroll
        for (int j = 0; j < 2; ++j)
          acc[i + 4][j] = __builtin_amdgcn_mfma_f32_16x16x32_bf16(a_[i][s], b_[j][s], acc[i + 4][j], 0, 0, 0);
    __builtin_amdgcn_s_setprio(0);
    __builtin_amdgcn_sched_barrier(0);
    __builtin_amdgcn_s_barrier();
    __builtin_amdgcn_sched_barrier(0);
  }

  // epilogue: C/D map col=lane&15, row=(lane>>4)*4+rr (m89-verified)
  const int q4 = (lane >> 4) << 2;
  if (MODE == 0) {
    #pragma unroll
    for (int i = 0; i < 8; ++i) {
      #pragma unroll
      for (int j = 0; j < 4; ++j) {
        const int nloc = wn + (j << 4) + (lane & 15);
        const float bb = bias[e * HID + hb + nb + nloc];
        #pragma unroll
        for (int rr = 0; rr < 4; ++rr) {
          const int m = m0 + wm + (i << 4) + q4 + rr;
          if (m < n_e) {
            float v = acc[i][j][rr] + bb;
            v = v / (1.0f + __expf(-v));                 // silu
            hout[(size_t)(offs[e] + m) * Hs + nb + nloc] = f2bf(v);
          }
        }
      }
    }
  } else {
    #pragma unroll
    for (int i = 0; i < 8; ++i) {
      #pragma unroll
      for (int rr = 0; rr < 4; ++rr) {
        const int m = m0 + wm + (i << 4) + q4 + rr;
        if (m < n_e) {
          const int   tok = lists_tok[e * NTOK + m];
          const float pp  = lists_p[e * NTOK + m];
          #pragma unroll
          for (int j = 0; j < 4; ++j) {
            const int d = nb + wn + (j << 4) + (lane & 15);
            float v = acc[i][j][rr];
            if (hb == 0) v += bias[e * DIM + d];   // add b2 exactly once (slice 0)
            atomicAdd(out + (size_t)tok * DIM + d, pp * v);
          }
        }
      }
    }
  }
}

extern "C" void kernel_launch(void* const* d_in, const int* in_sizes, int n_in,
                              void* d_out, int out_size, void* d_ws, size_t ws_size,
                              hipStream_t stream)
{
  const float* x      = (const float*)d_in[0];
  const float* gate_w = (const float*)d_in[1];
  const float* gate_b = (const float*)d_in[2];
  const float* w1     = (const float*)d_in[3];
  const float* b1     = (const float*)d_in[4];
  const float* w2     = (const float*)d_in[5];
  const float* b2     = (const float*)d_in[6];
  const float* noise  = (const float*)d_in[7];
  float* out = (float*)d_out;

  char* ws = (char*)d_ws;
  const size_t CNT_OFF = 0;          // int counts[8]
  const size_t OFF_OFF = 64;         // int offs[9]
  const size_t NBK_OFF = 128;        // int nblk[1]
  const size_t TBE_OFF = 192;        // int tbl_e[72]
  const size_t TBM_OFF = 1024;       // int tbl_m[72]
  const size_t LT_OFF  = 2048;       // int  lists_tok[8][8192]   (256 KB)
  const size_t LP_OFF  = LT_OFF + 262144;
  const size_t PA_OFF  = LP_OFF + 262144;
  const size_t XB_OFF  = 1048576;    // bf16 xb[8192][1024]       (16 MB)
  const size_t W_OFF   = 17825792;   // bf16 weight-slice buffer  (32 MB / nsl), then h

  // pick H-slicing: need = W_OFF + 32MB/nsl (wt) + 64MB/nsl (h); Hs >= 256 required
  int nsl = 0;
  for (int cand = 1; cand <= 8; cand <<= 1) {
    const size_t need = W_OFF + (size_t)(33554432 + 67108864) / (size_t)cand;
    if (ws_size >= need) { nsl = cand; break; }
  }
  if (!nsl) return;
  const int Hs = HID / nsl;

  int* counts          = (int*)(ws + CNT_OFF);
  int* offs            = (int*)(ws + OFF_OFF);
  int* nblk            = (int*)(ws + NBK_OFF);
  int* tbl_e           = (int*)(ws + TBE_OFF);
  int* tbl_m           = (int*)(ws + TBM_OFF);
  int* lists_tok       = (int*)(ws + LT_OFF);
  float* lists_p       = (float*)(ws + LP_OFF);
  float* probs_all     = (float*)(ws + PA_OFF);
  unsigned short* xb   = (unsigned short*)(ws + XB_OFF);
  unsigned short* wt   = (unsigned short*)(ws + W_OFF);
  unsigned short* hbuf = (unsigned short*)(ws + W_OFF + (size_t)33554432 / nsl);

  hipMemsetAsync(d_out, 0, (size_t)OUT_MAIN * sizeof(float), stream);
  hipMemsetAsync(ws + CNT_OFF, 0, 64, stream);

  k_gating<<<NTOK / 16, 1024, 0, stream>>>(x, gate_w, gate_b, noise, out, counts,
                                           lists_tok, lists_p, probs_all, xb);
  k_offs<<<1, 64, 0, stream>>>(counts, offs, tbl_e, tbl_m, nblk);
  k_aux<<<1, 256, 0, stream>>>(probs_all, out);

  for (int s = 0; s < nsl; ++s) {
    const int hb = s * Hs;
    // w1t slice: w1[e][d][h], rows d (1024), cols h in [hb,hb+Hs) -> wt[e][h'][d]
    dim3 gt1(DIM / 64, Hs / 64, NEXP);
    k_tr<<<gt1, 256, 0, stream>>>(w1, wt, HID, (size_t)DIM * HID, 0, hb,
                                  DIM, (size_t)Hs * DIM);
    dim3 g1(MAXBLK, Hs / 256, 1);
    k_gemm<0><<<g1, 512, 0, stream>>>(xb, wt, b1, counts, offs, tbl_e, tbl_m, nblk,
                                      lists_tok, lists_p, hbuf, out, hb, Hs);
    // w2t slice: w2[e][h][d], rows h in [hb,hb+Hs), cols d (1024) -> wt[e][d][h']
    dim3 gt2(Hs / 64, DIM / 64, NEXP);
    k_tr<<<gt2, 256, 0, stream>>>(w2, wt, DIM, (size_t)DIM * HID, hb, 0,
                                  Hs, (size_t)DIM * Hs);
    dim3 g2(MAXBLK, DIM / 256, 1);   // no split-K
    k_gemm<1><<<g2, 512, 0, stream>>>(hbuf, wt, b2, counts, offs, tbl_e, tbl_m, nblk,
                                      lists_tok, lists_p, hbuf, out, hb, Hs);
  }
}

// Round 6
// 483.778 us; speedup vs baseline: 1.0260x; 1.0260x over previous
//
#include <hip/hip_runtime.h>
#include <stdint.h>

// SparseMoE: B=4,S=2048,D=1024,E=8,H=2048, top-k=2.
// Outputs (concat, float32): final_output[8192*1024], top_k_indices[8192*2] (as floats), aux_loss[1].

#define NTOK   8192
#define DIM    1024
#define NEXP   8
#define HID    2048
#define OUT_MAIN (NTOK * DIM)          // 8388608
#define IDX_OFF  OUT_MAIN
#define AUX_OFF  (OUT_MAIN + NTOK * 2) // 8404992
#define MAXBLK 72                      // >= 64 + 7 worst-case 256-row m-blocks over 8 experts

typedef __attribute__((ext_vector_type(8))) short short8;
typedef __attribute__((ext_vector_type(4))) float floatx4;

__device__ __forceinline__ unsigned short f2bf(float f) {
  unsigned int b = __float_as_uint(f);
  b += 0x7FFFu + ((b >> 16) & 1u);      // RNE; inputs finite
  return (unsigned short)(b >> 16);
}

// ---------------- gating: logits (fp64 acc), top-2, masked softmax, scatter, xb=bf16(x) ---
__global__ __launch_bounds__(1024) void k_gating(
    const float* __restrict__ x, const float* __restrict__ gate_w,
    const float* __restrict__ gate_b, const float* __restrict__ noise,
    float* __restrict__ out, int* __restrict__ counts,
    int* __restrict__ lists_tok, float* __restrict__ lists_p,
    float* __restrict__ probs_all, unsigned short* __restrict__ xb)
{
  const int lane = threadIdx.x & 63;
  const int wv   = threadIdx.x >> 6;              // 0..15
  const int t    = blockIdx.x * 16 + wv;          // one token per wave
  const float* xr = x + (size_t)t * DIM;

  __shared__ int   cnt[NEXP];
  __shared__ int   base[NEXP];
  __shared__ int   s_e[32];
  __shared__ int   s_pos[32];
  __shared__ float s_p[32];
  if (threadIdx.x < NEXP) cnt[threadIdx.x] = 0;

  double acc[NEXP] = {0,0,0,0,0,0,0,0};
  #pragma unroll
  for (int jj = 0; jj < 4; ++jj) {
    const int d0 = lane * 4 + jj * 256;
    const float4 xv = *(const float4*)(xr + d0);
    const float xs[4] = {xv.x, xv.y, xv.z, xv.w};
    unsigned short xbq[4];
    #pragma unroll
    for (int c = 0; c < 4; ++c) {
      const float4 g0 = *(const float4*)(gate_w + (size_t)(d0 + c) * NEXP);
      const float4 g1 = *(const float4*)(gate_w + (size_t)(d0 + c) * NEXP + 4);
      const double xd = (double)xs[c];
      acc[0] += xd * (double)g0.x; acc[1] += xd * (double)g0.y;
      acc[2] += xd * (double)g0.z; acc[3] += xd * (double)g0.w;
      acc[4] += xd * (double)g1.x; acc[5] += xd * (double)g1.y;
      acc[6] += xd * (double)g1.z; acc[7] += xd * (double)g1.w;
      xbq[c] = f2bf(xs[c]);
    }
    ushort4 q; q.x = xbq[0]; q.y = xbq[1]; q.z = xbq[2]; q.w = xbq[3];
    *(ushort4*)(xb + (size_t)t * DIM + d0) = q;
  }
  #pragma unroll
  for (int e = 0; e < NEXP; ++e) {
    #pragma unroll
    for (int off = 32; off; off >>= 1) acc[e] += __shfl_xor(acc[e], off);
  }
  __syncthreads();                                 // cnt[] initialized
  if (lane == 0) {
    double l[NEXP];
    #pragma unroll
    for (int e = 0; e < NEXP; ++e)
      l[e] = acc[e] + (double)gate_b[e] + 0.01 * (double)noise[(size_t)t * NEXP + e];
    int i1 = 0; double v1 = l[0];
    #pragma unroll
    for (int e = 1; e < NEXP; ++e) if (l[e] > v1) { v1 = l[e]; i1 = e; }
    int i2 = (i1 == 0) ? 1 : 0; double v2 = l[i2];
    #pragma unroll
    for (int e = 0; e < NEXP; ++e) if (e != i1 && l[e] > v2) { v2 = l[e]; i2 = e; }
    float pr[NEXP]; float Z = 0.f;
    #pragma unroll
    for (int e = 0; e < NEXP; ++e) {
      const float a = (l[e] >= v2) ? (float)(l[e] - v1) : -1.0e9f;
      pr[e] = __expf(a); Z += pr[e];
    }
    const float rz = 1.0f / Z;
    #pragma unroll
    for (int e = 0; e < NEXP; ++e) {
      pr[e] *= rz;
      probs_all[(size_t)t * NEXP + e] = pr[e];
    }
    out[(size_t)IDX_OFF + t * 2]     = (float)i1;
    out[(size_t)IDX_OFF + t * 2 + 1] = (float)i2;
    const int p1 = atomicAdd(&cnt[i1], 1);
    const int p2 = atomicAdd(&cnt[i2], 1);
    s_e[wv * 2]     = i1; s_pos[wv * 2]     = p1; s_p[wv * 2]     = pr[i1];
    s_e[wv * 2 + 1] = i2; s_pos[wv * 2 + 1] = p2; s_p[wv * 2 + 1] = pr[i2];
  }
  __syncthreads();
  if (threadIdx.x < NEXP) base[threadIdx.x] = atomicAdd(&counts[threadIdx.x], cnt[threadIdx.x]);
  __syncthreads();
  if (lane == 0) {
    #pragma unroll
    for (int k = 0; k < 2; ++k) {
      const int ee  = s_e[wv * 2 + k];
      const int pos = base[ee] + s_pos[wv * 2 + k];
      lists_tok[ee * NTOK + pos] = t;
      lists_p[ee * NTOK + pos]   = s_p[wv * 2 + k];
    }
  }
}

// ---------------- offsets + balanced XCD-local block table (256-row m-granularity) -----
// HW assigns XCD = linear_block_id % 8; gridDim.x=72 (≡0 mod 8) -> XCD = bx%8 for all by.
// XCD class c = pos%8 gets a CONTIGUOUS run of valid entries (expert/B-slice L2 locality)
// partitioned balanced over the VALID count. Invalid slots = -1.
__global__ void k_offs(const int* __restrict__ counts, int* __restrict__ offs,
                       int* __restrict__ tbl_e, int* __restrict__ tbl_m,
                       int* __restrict__ nblk) {
  if (threadIdx.x == 0) {
    int a = 0;
    #pragma unroll
    for (int e = 0; e < NEXP; ++e) { offs[e] = a; a += counts[e]; }
    offs[NEXP] = a;
    int ent_e[MAXBLK], ent_m[MAXBLK];
    int nb = 0;
    for (int e = 0; e < NEXP; ++e) {
      const int nbe = (counts[e] + 255) >> 8;
      for (int m = 0; m < nbe; ++m) { ent_e[nb] = e; ent_m[nb] = m << 8; ++nb; }
    }
    nblk[0] = nb;
    for (int p = 0; p < MAXBLK; ++p) { tbl_e[p] = -1; tbl_m[p] = 0; }
    const int q = nb >> 3, r = nb & 7;
    for (int c = 0; c < 8; ++c) {
      const int cnt   = q + (c < r ? 1 : 0);          // <= 9
      const int start = c * q + (c < r ? c : r);
      for (int t = 0; t < cnt; ++t) {
        const int pos = c + (t << 3);                 // pos%8 == c, pos < 72
        tbl_e[pos] = ent_e[start + t];
        tbl_m[pos] = ent_m[start + t];
      }
    }
  }
}

// ---------------- aux loss ----------------
__global__ __launch_bounds__(256) void k_aux(const float* __restrict__ probs_all,
                                             float* __restrict__ out) {
  float p[NEXP] = {0,0,0,0,0,0,0,0};
  for (int t = threadIdx.x; t < NTOK; t += 256) {
    const float4 a = *(const float4*)(probs_all + (size_t)t * NEXP);
    const float4 b = *(const float4*)(probs_all + (size_t)t * NEXP + 4);
    p[0] += a.x; p[1] += a.y; p[2] += a.z; p[3] += a.w;
    p[4] += b.x; p[5] += b.y; p[6] += b.z; p[7] += b.w;
  }
  #pragma unroll
  for (int e = 0; e < NEXP; ++e) {
    #pragma unroll
    for (int off = 32; off; off >>= 1) p[e] += __shfl_xor(p[e], off);
  }
  __shared__ float red[4][NEXP];
  const int lane = threadIdx.x & 63, wv = threadIdx.x >> 6;
  if (lane == 0) {
    #pragma unroll
    for (int e = 0; e < NEXP; ++e) red[wv][e] = p[e];
  }
  __syncthreads();
  if (threadIdx.x == 0) {
    float usage[NEXP], s = 0.f;
    #pragma unroll
    for (int e = 0; e < NEXP; ++e) {
      usage[e] = red[0][e] + red[1][e] + red[2][e] + red[3][e];
      s += usage[e];
    }
    float imp[NEXP], mean = 0.f, var = 0.f;
    #pragma unroll
    for (int e = 0; e < NEXP; ++e) { imp[e] = usage[e] / s; mean += imp[e]; }
    mean *= 0.125f;
    #pragma unroll
    for (int e = 0; e < NEXP; ++e) { const float d = imp[e] - mean; var += d * d; }
    var *= 0.125f;
    out[AUX_OFF] = sqrtf(var) / (mean + 1e-10f);
  }
}

// ---------------- weight transpose+convert: in[e][r][c] fp32 -> out[e][c-c0][r-r0] bf16 ---
__global__ __launch_bounds__(256) void k_tr(
    const float* __restrict__ in, unsigned short* __restrict__ out,
    int in_ld, size_t in_estride, int r0, int c0,
    int out_ld, size_t out_estride)
{
  const int e  = blockIdx.z;
  const int tr = blockIdx.x << 6;
  const int tc = blockIdx.y << 6;
  const int tid = threadIdx.x;
  __shared__ float t[64][65];
  const float* src = in + (size_t)e * in_estride + (size_t)(r0 + tr) * in_ld + (c0 + tc);
  #pragma unroll
  for (int p = 0; p < 4; ++p) {
    const int r  = (p << 4) + (tid >> 4);
    const int c4 = (tid & 15) << 2;
    const float4 v = *(const float4*)(src + (size_t)r * in_ld + c4);
    t[r][c4] = v.x; t[r][c4 + 1] = v.y; t[r][c4 + 2] = v.z; t[r][c4 + 3] = v.w;
  }
  __syncthreads();
  unsigned short* dst = out + (size_t)e * out_estride + (size_t)tc * out_ld + tr;
  #pragma unroll
  for (int p = 0; p < 4; ++p) {
    const int c  = (p << 4) + (tid >> 4);
    const int r4 = (tid & 15) << 2;
    ushort4 q;
    q.x = f2bf(t[r4][c]);     q.y = f2bf(t[r4 + 1][c]);
    q.z = f2bf(t[r4 + 2][c]); q.w = f2bf(t[r4 + 3][c]);
    *(ushort4*)(dst + (size_t)c * out_ld + r4) = q;
  }
}

// ---------------- grouped MFMA GEMM: 256x256 tile, 8 waves, BK=64, counted-vmcnt pipe ---
// r3-verified loop (2-barrier/tile, counted vmcnt never 0 mid-loop, sched_barrier fences,
// setprio MFMA clusters, compiler-managed lgkmcnt) with m230-V0 wave geometry:
// 8 waves 2Mx4N, per-wave 128x64 out (acc[8][4]) -> per wave per K-tile: 64 MFMA vs 32,
// 24 ds_read_b128 vs 16, half the staging calls, half the barrier participants.
// MODE 0: h[slot, nb+n] = silu( xb[tok] @ w1t[e][nb+n][:] + b1 )   (K = 1024)
// MODE 1 (split-K=2): out[tok, nb+n] += p * ( h[slot] @ w2t[e][nb+n][:] + b2 )
// LDS [row][64] 16B-chunk XOR swizzle (r3-verified, conflicts=0): LDS[r][j]=glob[r][j^(r&7)].
template <int MODE>
__global__ __launch_bounds__(512, 2) void k_gemm(
    const unsigned short* __restrict__ Abase,
    const unsigned short* __restrict__ Bt,
    const float* __restrict__ bias,
    const int* __restrict__ counts, const int* __restrict__ offs,
    const int* __restrict__ tbl_e, const int* __restrict__ tbl_m,
    const int* __restrict__ nblk,
    const int* __restrict__ lists_tok, const float* __restrict__ lists_p,
    unsigned short* __restrict__ hout, float* __restrict__ out,
    const int hb, const int Hs)
{
  const int bx = blockIdx.x;
  const int e  = tbl_e[bx];
  if (e < 0) return;
  const int m0  = tbl_m[bx];
  const int n_e = counts[e];
  const int by  = blockIdx.y;

  int nb, k0g, Kloc;
  if (MODE == 0) { nb = by << 8; k0g = 0; Kloc = DIM; }
  else { nb = (by >> 1) << 8; const int half = Hs >> 1;
         k0g = (by & 1) * half; Kloc = half; }

  const int tid  = threadIdx.x;
  const int lane = tid & 63;
  const int wv   = tid >> 6;                 // 0..7
  const int wm   = (wv & 1) << 7;            // 0 / 128
  const int wn   = (wv >> 1) << 6;           // 0 / 64 / 128 / 192

  __shared__ __align__(16) unsigned short as[2][256 * 64];  // 2 x 32 KB
  __shared__ __align__(16) unsigned short bs[2][256 * 64];  // 2 x 32 KB

  const int K = (MODE == 0) ? DIM : Hs;      // row stride of both A and B
  const unsigned short* Bexp = Bt + (size_t)e * ((size_t)DIM * Hs) + (size_t)nb * K + k0g;

  // staging: 8 gload_lds calls per wave per K-tile (4 A-groups + 4 B-groups of 8 rows).
  // lane l covers row grp+(l>>3), chunk l&7; source chunk (l&7)^(l>>3) -> swizzled LDS
  // LDS[r][j] = glob[r][j^(r&7)]  (group base ≡ 0 mod 8).
  const int off_sh = ((lane & 7) ^ (lane >> 3)) << 3;   // shorts
  const int rA = (wv << 5) + (lane >> 3);               // wave's 32-row band, rows rA+8k
  const unsigned short* pA[4];
  #pragma unroll
  for (int k = 0; k < 4; ++k) {
    const int rr = m0 + rA + (k << 3);
    const int rc = (rr < n_e) ? rr : (n_e - 1);
    size_t arow;
    if (MODE == 0) arow = (size_t)lists_tok[e * NTOK + rc] * DIM;
    else           arow = (size_t)(offs[e] + rc) * Hs;
    pA[k] = Abase + arow + k0g + off_sh;
  }
  const unsigned short* pB[4];
  #pragma unroll
  for (int k = 0; k < 4; ++k)
    pB[k] = Bexp + (size_t)(rA + (k << 3)) * K + off_sh;
  const int dbase = (wv << 5) * 64;                     // shorts; +8*64 per group

  auto issue = [&](int buf, int kk) {
    unsigned short* a0 = (buf ? &as[1][0] : &as[0][0]) + dbase;
    unsigned short* b0 = (buf ? &bs[1][0] : &bs[0][0]) + dbase;
    #pragma unroll
    for (int k = 0; k < 4; ++k) {
      __builtin_amdgcn_global_load_lds(
          (const __attribute__((address_space(1))) void*)(pA[k] + kk),
          (__attribute__((address_space(3))) void*)(void*)(a0 + k * 8 * 64), 16, 0, 0);
      __builtin_amdgcn_global_load_lds(
          (const __attribute__((address_space(1))) void*)(pB[k] + kk),
          (__attribute__((address_space(3))) void*)(void*)(b0 + k * 8 * 64), 16, 0, 0);
    }
  };

  floatx4 acc[8][4];
  #pragma unroll
  for (int i = 0; i < 8; ++i)
    #pragma unroll
    for (int j = 0; j < 4; ++j) acc[i][j] = (floatx4){0.f, 0.f, 0.f, 0.f};

  const int nt = Kloc >> 6;                  // >= 2 for all configs (Hs >= 256)
  issue(0, 0);
  issue(1, 64);
  int p = 0;
  for (int t = 0; t < nt; ++t) {
    // tile t complete; tile t+1's 8 calls stay in flight across the barrier (T4)
    if (t + 1 < nt) { asm volatile("s_waitcnt vmcnt(8)" ::: "memory"); }
    else            { asm volatile("s_waitcnt vmcnt(0)" ::: "memory"); }
    __builtin_amdgcn_sched_barrier(0);
    __builtin_amdgcn_s_barrier();
    __builtin_amdgcn_sched_barrier(0);
    const unsigned short* ap = p ? &as[1][0] : &as[0][0];
    const unsigned short* bp = p ? &bs[1][0] : &bs[0][0];
    const int c = lane >> 4;                 // 16B-chunk within 32-col k-slot
    #pragma unroll
    for (int s = 0; s < 2; ++s) {            // two k-slots of 32 per K-tile
      short8 af[8], bfr[4];
      #pragma unroll
      for (int i = 0; i < 8; ++i) {
        const int row = wm + (i << 4) + (lane & 15);
        af[i] = *(const short8*)(ap + row * 64 + ((((s << 2) | c) ^ (row & 7)) << 3));
      }
      #pragma unroll
      for (int j = 0; j < 4; ++j) {
        const int row = wn + (j << 4) + (lane & 15);
        bfr[j] = *(const short8*)(bp + row * 64 + ((((s << 2) | c) ^ (row & 7)) << 3));
      }
      __builtin_amdgcn_s_setprio(1);
      #pragma unroll
      for (int i = 0; i < 8; ++i)
        #pragma unroll
        for (int j = 0; j < 4; ++j)
          acc[i][j] = __builtin_amdgcn_mfma_f32_16x16x32_bf16(af[i], bfr[j], acc[i][j], 0, 0, 0);
      __builtin_amdgcn_s_setprio(0);
    }
    __builtin_amdgcn_sched_barrier(0);
    __builtin_amdgcn_s_barrier();            // all waves done reading buf p
    __builtin_amdgcn_sched_barrier(0);
    if (t + 2 < nt) issue(p, (t + 2) << 6);  // overwrite tile t's buffer (safe)
    p ^= 1;
  }

  // epilogue: C/D map col=lane&15, row=(lane>>4)*4+rr (m89-verified)
  const int q4 = (lane >> 4) << 2;
  if (MODE == 0) {
    #pragma unroll
    for (int i = 0; i < 8; ++i) {
      #pragma unroll
      for (int j = 0; j < 4; ++j) {
        const int nloc = wn + (j << 4) + (lane & 15);
        const float bb = bias[e * HID + hb + nb + nloc];
        #pragma unroll
        for (int rr = 0; rr < 4; ++rr) {
          const int m = m0 + wm + (i << 4) + q4 + rr;
          if (m < n_e) {
            float v = acc[i][j][rr] + bb;
            v = v / (1.0f + __expf(-v));                 // silu
            hout[(size_t)(offs[e] + m) * Hs + nb + nloc] = f2bf(v);
          }
        }
      }
    }
  } else {
    #pragma unroll
    for (int i = 0; i < 8; ++i) {
      #pragma unroll
      for (int rr = 0; rr < 4; ++rr) {
        const int m = m0 + wm + (i << 4) + q4 + rr;
        if (m < n_e) {
          const int   tok = lists_tok[e * NTOK + m];
          const float pp  = lists_p[e * NTOK + m];
          #pragma unroll
          for (int j = 0; j < 4; ++j) {
            const int d = nb + wn + (j << 4) + (lane & 15);
            float v = acc[i][j][rr];
            if (hb == 0 && k0g == 0) v += bias[e * DIM + d];   // add b2 exactly once
            atomicAdd(out + (size_t)tok * DIM + d, pp * v);
          }
        }
      }
    }
  }
}

extern "C" void kernel_launch(void* const* d_in, const int* in_sizes, int n_in,
                              void* d_out, int out_size, void* d_ws, size_t ws_size,
                              hipStream_t stream)
{
  const float* x      = (const float*)d_in[0];
  const float* gate_w = (const float*)d_in[1];
  const float* gate_b = (const float*)d_in[2];
  const float* w1     = (const float*)d_in[3];
  const float* b1     = (const float*)d_in[4];
  const float* w2     = (const float*)d_in[5];
  const float* b2     = (const float*)d_in[6];
  const float* noise  = (const float*)d_in[7];
  float* out = (float*)d_out;

  char* ws = (char*)d_ws;
  const size_t CNT_OFF = 0;          // int counts[8]
  const size_t OFF_OFF = 64;         // int offs[9]
  const size_t NBK_OFF = 128;        // int nblk[1]
  const size_t TBE_OFF = 192;        // int tbl_e[72]
  const size_t TBM_OFF = 1024;       // int tbl_m[72]
  const size_t LT_OFF  = 2048;       // int  lists_tok[8][8192]   (256 KB)
  const size_t LP_OFF  = LT_OFF + 262144;
  const size_t PA_OFF  = LP_OFF + 262144;
  const size_t XB_OFF  = 1048576;    // bf16 xb[8192][1024]       (16 MB)
  const size_t W_OFF   = 17825792;   // bf16 weight-slice buffer  (32 MB / nsl), then h

  // pick H-slicing: need = W_OFF + 32MB/nsl (wt) + 64MB/nsl (h); Hs >= 256 required
  int nsl = 0;
  for (int cand = 1; cand <= 8; cand <<= 1) {
    const size_t need = W_OFF + (size_t)(33554432 + 67108864) / (size_t)cand;
    if (ws_size >= need) { nsl = cand; break; }
  }
  if (!nsl) return;
  const int Hs = HID / nsl;

  int* counts          = (int*)(ws + CNT_OFF);
  int* offs            = (int*)(ws + OFF_OFF);
  int* nblk            = (int*)(ws + NBK_OFF);
  int* tbl_e           = (int*)(ws + TBE_OFF);
  int* tbl_m           = (int*)(ws + TBM_OFF);
  int* lists_tok       = (int*)(ws + LT_OFF);
  float* lists_p       = (float*)(ws + LP_OFF);
  float* probs_all     = (float*)(ws + PA_OFF);
  unsigned short* xb   = (unsigned short*)(ws + XB_OFF);
  unsigned short* wt   = (unsigned short*)(ws + W_OFF);
  unsigned short* hbuf = (unsigned short*)(ws + W_OFF + (size_t)33554432 / nsl);

  hipMemsetAsync(d_out, 0, (size_t)OUT_MAIN * sizeof(float), stream);
  hipMemsetAsync(ws + CNT_OFF, 0, 64, stream);

  k_gating<<<NTOK / 16, 1024, 0, stream>>>(x, gate_w, gate_b, noise, out, counts,
                                           lists_tok, lists_p, probs_all, xb);
  k_offs<<<1, 64, 0, stream>>>(counts, offs, tbl_e, tbl_m, nblk);
  k_aux<<<1, 256, 0, stream>>>(probs_all, out);

  for (int s = 0; s < nsl; ++s) {
    const int hb = s * Hs;
    // w1t slice: w1[e][d][h], rows d (1024), cols h in [hb,hb+Hs) -> wt[e][h'][d]
    dim3 gt1(DIM / 64, Hs / 64, NEXP);
    k_tr<<<gt1, 256, 0, stream>>>(w1, wt, HID, (size_t)DIM * HID, 0, hb,
                                  DIM, (size_t)Hs * DIM);
    dim3 g1(MAXBLK, Hs / 256, 1);
    k_gemm<0><<<g1, 512, 0, stream>>>(xb, wt, b1, counts, offs, tbl_e, tbl_m, nblk,
                                      lists_tok, lists_p, hbuf, out, hb, Hs);
    // w2t slice: w2[e][h][d], rows h in [hb,hb+Hs), cols d (1024) -> wt[e][d][h']
    dim3 gt2(Hs / 64, DIM / 64, NEXP);
    k_tr<<<gt2, 256, 0, stream>>>(w2, wt, DIM, (size_t)DIM * HID, hb, 0,
                                  Hs, (size_t)DIM * Hs);
    dim3 g2(MAXBLK, (DIM / 256) * 2, 1);   // x2 = split-K
    k_gemm<1><<<g2, 512, 0, stream>>>(hbuf, wt, b2, counts, offs, tbl_e, tbl_m, nblk,
                                      lists_tok, lists_p, hbuf, out, hb, Hs);
  }
}

// Round 7
// 467.337 us; speedup vs baseline: 1.0621x; 1.0352x over previous
//
#include <hip/hip_runtime.h>
#include <stdint.h>

// SparseMoE: B=4,S=2048,D=1024,E=8,H=2048, top-k=2.
// Outputs (concat, float32): final_output[8192*1024], top_k_indices[8192*2] (as floats), aux_loss[1].

#define NTOK   8192
#define DIM    1024
#define NEXP   8
#define HID    2048
#define OUT_MAIN (NTOK * DIM)          // 8388608
#define IDX_OFF  OUT_MAIN
#define AUX_OFF  (OUT_MAIN + NTOK * 2) // 8404992
#define MAXBLK 72                      // >= 64 + 7 worst-case 256-row m-blocks over 8 experts

typedef __attribute__((ext_vector_type(8))) short short8;
typedef __attribute__((ext_vector_type(4))) float floatx4;

__device__ __forceinline__ unsigned short f2bf(float f) {
  unsigned int b = __float_as_uint(f);
  b += 0x7FFFu + ((b >> 16) & 1u);      // RNE; inputs finite
  return (unsigned short)(b >> 16);
}

// ---------------- gating: logits (fp64 acc), top-2, masked softmax, scatter, xb=bf16(x) ---
__global__ __launch_bounds__(1024) void k_gating(
    const float* __restrict__ x, const float* __restrict__ gate_w,
    const float* __restrict__ gate_b, const float* __restrict__ noise,
    float* __restrict__ out, int* __restrict__ counts,
    int* __restrict__ lists_tok, float* __restrict__ lists_p,
    float* __restrict__ probs_all, unsigned short* __restrict__ xb)
{
  const int lane = threadIdx.x & 63;
  const int wv   = threadIdx.x >> 6;              // 0..15
  const int t    = blockIdx.x * 16 + wv;          // one token per wave
  const float* xr = x + (size_t)t * DIM;

  __shared__ int   cnt[NEXP];
  __shared__ int   base[NEXP];
  __shared__ int   s_e[32];
  __shared__ int   s_pos[32];
  __shared__ float s_p[32];
  if (threadIdx.x < NEXP) cnt[threadIdx.x] = 0;

  double acc[NEXP] = {0,0,0,0,0,0,0,0};
  #pragma unroll
  for (int jj = 0; jj < 4; ++jj) {
    const int d0 = lane * 4 + jj * 256;
    const float4 xv = *(const float4*)(xr + d0);
    const float xs[4] = {xv.x, xv.y, xv.z, xv.w};
    unsigned short xbq[4];
    #pragma unroll
    for (int c = 0; c < 4; ++c) {
      const float4 g0 = *(const float4*)(gate_w + (size_t)(d0 + c) * NEXP);
      const float4 g1 = *(const float4*)(gate_w + (size_t)(d0 + c) * NEXP + 4);
      const double xd = (double)xs[c];
      acc[0] += xd * (double)g0.x; acc[1] += xd * (double)g0.y;
      acc[2] += xd * (double)g0.z; acc[3] += xd * (double)g0.w;
      acc[4] += xd * (double)g1.x; acc[5] += xd * (double)g1.y;
      acc[6] += xd * (double)g1.z; acc[7] += xd * (double)g1.w;
      xbq[c] = f2bf(xs[c]);
    }
    ushort4 q; q.x = xbq[0]; q.y = xbq[1]; q.z = xbq[2]; q.w = xbq[3];
    *(ushort4*)(xb + (size_t)t * DIM + d0) = q;
  }
  #pragma unroll
  for (int e = 0; e < NEXP; ++e) {
    #pragma unroll
    for (int off = 32; off; off >>= 1) acc[e] += __shfl_xor(acc[e], off);
  }
  __syncthreads();                                 // cnt[] initialized
  if (lane == 0) {
    double l[NEXP];
    #pragma unroll
    for (int e = 0; e < NEXP; ++e)
      l[e] = acc[e] + (double)gate_b[e] + 0.01 * (double)noise[(size_t)t * NEXP + e];
    int i1 = 0; double v1 = l[0];
    #pragma unroll
    for (int e = 1; e < NEXP; ++e) if (l[e] > v1) { v1 = l[e]; i1 = e; }
    int i2 = (i1 == 0) ? 1 : 0; double v2 = l[i2];
    #pragma unroll
    for (int e = 0; e < NEXP; ++e) if (e != i1 && l[e] > v2) { v2 = l[e]; i2 = e; }
    float pr[NEXP]; float Z = 0.f;
    #pragma unroll
    for (int e = 0; e < NEXP; ++e) {
      const float a = (l[e] >= v2) ? (float)(l[e] - v1) : -1.0e9f;
      pr[e] = __expf(a); Z += pr[e];
    }
    const float rz = 1.0f / Z;
    #pragma unroll
    for (int e = 0; e < NEXP; ++e) {
      pr[e] *= rz;
      probs_all[(size_t)t * NEXP + e] = pr[e];
    }
    out[(size_t)IDX_OFF + t * 2]     = (float)i1;
    out[(size_t)IDX_OFF + t * 2 + 1] = (float)i2;
    const int p1 = atomicAdd(&cnt[i1], 1);
    const int p2 = atomicAdd(&cnt[i2], 1);
    s_e[wv * 2]     = i1; s_pos[wv * 2]     = p1; s_p[wv * 2]     = pr[i1];
    s_e[wv * 2 + 1] = i2; s_pos[wv * 2 + 1] = p2; s_p[wv * 2 + 1] = pr[i2];
  }
  __syncthreads();
  if (threadIdx.x < NEXP) base[threadIdx.x] = atomicAdd(&counts[threadIdx.x], cnt[threadIdx.x]);
  __syncthreads();
  if (lane == 0) {
    #pragma unroll
    for (int k = 0; k < 2; ++k) {
      const int ee  = s_e[wv * 2 + k];
      const int pos = base[ee] + s_pos[wv * 2 + k];
      lists_tok[ee * NTOK + pos] = t;
      lists_p[ee * NTOK + pos]   = s_p[wv * 2 + k];
    }
  }
}

// ---------------- offsets + balanced XCD-local block table (256-row m-granularity) -----
__global__ void k_offs(const int* __restrict__ counts, int* __restrict__ offs,
                       int* __restrict__ tbl_e, int* __restrict__ tbl_m,
                       int* __restrict__ nblk) {
  if (threadIdx.x == 0) {
    int a = 0;
    #pragma unroll
    for (int e = 0; e < NEXP; ++e) { offs[e] = a; a += counts[e]; }
    offs[NEXP] = a;
    int ent_e[MAXBLK], ent_m[MAXBLK];
    int nb = 0;
    for (int e = 0; e < NEXP; ++e) {
      const int nbe = (counts[e] + 255) >> 8;
      for (int m = 0; m < nbe; ++m) { ent_e[nb] = e; ent_m[nb] = m << 8; ++nb; }
    }
    nblk[0] = nb;
    for (int p = 0; p < MAXBLK; ++p) { tbl_e[p] = -1; tbl_m[p] = 0; }
    const int q = nb >> 3, r = nb & 7;
    for (int c = 0; c < 8; ++c) {
      const int cnt   = q + (c < r ? 1 : 0);          // <= 9
      const int start = c * q + (c < r ? c : r);
      for (int t = 0; t < cnt; ++t) {
        const int pos = c + (t << 3);                 // pos%8 == c, pos < 72
        tbl_e[pos] = ent_e[start + t];
        tbl_m[pos] = ent_m[start + t];
      }
    }
  }
}

// ---------------- aux loss ----------------
__global__ __launch_bounds__(256) void k_aux(const float* __restrict__ probs_all,
                                             float* __restrict__ out) {
  float p[NEXP] = {0,0,0,0,0,0,0,0};
  for (int t = threadIdx.x; t < NTOK; t += 256) {
    const float4 a = *(const float4*)(probs_all + (size_t)t * NEXP);
    const float4 b = *(const float4*)(probs_all + (size_t)t * NEXP + 4);
    p[0] += a.x; p[1] += a.y; p[2] += a.z; p[3] += a.w;
    p[4] += b.x; p[5] += b.y; p[6] += b.z; p[7] += b.w;
  }
  #pragma unroll
  for (int e = 0; e < NEXP; ++e) {
    #pragma unroll
    for (int off = 32; off; off >>= 1) p[e] += __shfl_xor(p[e], off);
  }
  __shared__ float red[4][NEXP];
  const int lane = threadIdx.x & 63, wv = threadIdx.x >> 6;
  if (lane == 0) {
    #pragma unroll
    for (int e = 0; e < NEXP; ++e) red[wv][e] = p[e];
  }
  __syncthreads();
  if (threadIdx.x == 0) {
    float usage[NEXP], s = 0.f;
    #pragma unroll
    for (int e = 0; e < NEXP; ++e) {
      usage[e] = red[0][e] + red[1][e] + red[2][e] + red[3][e];
      s += usage[e];
    }
    float imp[NEXP], mean = 0.f, var = 0.f;
    #pragma unroll
    for (int e = 0; e < NEXP; ++e) { imp[e] = usage[e] / s; mean += imp[e]; }
    mean *= 0.125f;
    #pragma unroll
    for (int e = 0; e < NEXP; ++e) { const float d = imp[e] - mean; var += d * d; }
    var *= 0.125f;
    out[AUX_OFF] = sqrtf(var) / (mean + 1e-10f);
  }
}

// ---------------- weight transpose+convert: in[e][r][c] fp32 -> out[e][c-c0][r-r0] bf16 ---
__global__ __launch_bounds__(256) void k_tr(
    const float* __restrict__ in, unsigned short* __restrict__ out,
    int in_ld, size_t in_estride, int r0, int c0,
    int out_ld, size_t out_estride)
{
  const int e  = blockIdx.z;
  const int tr = blockIdx.x << 6;
  const int tc = blockIdx.y << 6;
  const int tid = threadIdx.x;
  __shared__ float t[64][65];
  const float* src = in + (size_t)e * in_estride + (size_t)(r0 + tr) * in_ld + (c0 + tc);
  #pragma unroll
  for (int p = 0; p < 4; ++p) {
    const int r  = (p << 4) + (tid >> 4);
    const int c4 = (tid & 15) << 2;
    const float4 v = *(const float4*)(src + (size_t)r * in_ld + c4);
    t[r][c4] = v.x; t[r][c4 + 1] = v.y; t[r][c4 + 2] = v.z; t[r][c4 + 3] = v.w;
  }
  __syncthreads();
  unsigned short* dst = out + (size_t)e * out_estride + (size_t)tc * out_ld + tr;
  #pragma unroll
  for (int p = 0; p < 4; ++p) {
    const int c  = (p << 4) + (tid >> 4);
    const int r4 = (tid & 15) << 2;
    ushort4 q;
    q.x = f2bf(t[r4][c]);     q.y = f2bf(t[r4 + 1][c]);
    q.z = f2bf(t[r4 + 2][c]); q.w = f2bf(t[r4 + 3][c]);
    *(ushort4*)(dst + (size_t)c * out_ld + r4) = q;
  }
}

// ---------------- grouped MFMA GEMM: 256x256 tile, 8 waves, BK=64, 4-phase interleave ---
// m201-derived schedule, ledger-verified:
//  Per K-tile u (buf u&1): 4 quadrant phases (mLo,nLo)(mHi,nLo)(mHi,nHi)(mLo,nHi), each =
//  {1 stage event (2 gload_lds) ; 4-12 ds_read_b128 ; setprio(1) 16 MFMA setprio(0) ;
//   sched_barrier s_barrier sched_barrier}.  One barrier per phase; ph0 adds
//  vmcnt(6)+barrier (confirms ALL waves' tile-u staging; never vmcnt(0) mid-loop).
//  Frag retention sets region free-times: B-lo kept ph0->ph1, A-hi ph1->ph2, B-hi
//  ph2->ph3 => regions free one phase before their tile-u+2 overwrite:
//   u.ph0: A-lo(u+1)->other buf | u.ph1: B-lo(u+2)->cur | u.ph2: A-hi(u+2)->cur |
//   u.ph3: B-hi(u+2)->cur.   Ledger @u.ph0: 14 outstanding, oldest 8 = tile u -> vmcnt(6).
//  Overlap: next phase's ds_reads issue while previous MFMA cluster drains (pipes concurrent).
// MODE 0: h = silu(xb[tok] @ w1t + b1)  (K=1024).  MODE 1 split-K=2: out += p*(h @ w2t + b2).
// LDS [row][64] 16B-chunk XOR swizzle (r3-verified, conflicts=0): LDS[r][j]=glob[r][j^(r&7)].
template <int MODE>
__global__ __launch_bounds__(512, 2) void k_gemm(
    const unsigned short* __restrict__ Abase,
    const unsigned short* __restrict__ Bt,
    const float* __restrict__ bias,
    const int* __restrict__ counts, const int* __restrict__ offs,
    const int* __restrict__ tbl_e, const int* __restrict__ tbl_m,
    const int* __restrict__ nblk,
    const int* __restrict__ lists_tok, const float* __restrict__ lists_p,
    unsigned short* __restrict__ hout, float* __restrict__ out,
    const int hb, const int Hs)
{
  const int bx = blockIdx.x;
  const int e  = tbl_e[bx];
  if (e < 0) return;
  const int m0  = tbl_m[bx];
  const int n_e = counts[e];
  const int by  = blockIdx.y;

  int nb, k0g, Kloc;
  if (MODE == 0) { nb = by << 8; k0g = 0; Kloc = DIM; }
  else { nb = (by >> 1) << 8; const int half = Hs >> 1;
         k0g = (by & 1) * half; Kloc = half; }

  const int tid  = threadIdx.x;
  const int lane = tid & 63;
  const int wv   = tid >> 6;                 // 0..7
  const int wm   = (wv & 1) << 7;            // 0 / 128
  const int wn   = (wv >> 1) << 6;           // 0 / 64 / 128 / 192

  __shared__ __align__(16) unsigned short as[2][256 * 64];  // 2 x 32 KB
  __shared__ __align__(16) unsigned short bs[2][256 * 64];  // 2 x 32 KB
  unsigned short* const A0 = &as[0][0]; unsigned short* const A1 = &as[1][0];
  unsigned short* const B0 = &bs[0][0]; unsigned short* const B1 = &bs[1][0];

  const int K = (MODE == 0) ? DIM : Hs;      // row stride of both A and B
  const unsigned short* Bexp = Bt + (size_t)e * ((size_t)DIM * Hs) + (size_t)nb * K + k0g;

  // staging geometry: event = 128 rows x 64 cols = 2 gload_lds calls (512thr x 16B).
  // lane l covers row grp+(l>>3), chunk l&7; source chunk (l&7)^(l>>3) -> swizzled LDS.
  const int off_sh = ((lane & 7) ^ (lane >> 3)) << 3;   // shorts
  const int rw = (wv << 3) + (lane >> 3);               // 0..63
  // A pointers: rows (m0+) rw + {0,64,128,192}; A-lo event = {q0,q2}, A-hi = {q1,q3}
  const unsigned short* pA0; const unsigned short* pA1;
  const unsigned short* pA2; const unsigned short* pA3;
  {
    const unsigned short* p[4];
    #pragma unroll
    for (int q = 0; q < 4; ++q) {
      const int rr = m0 + rw + (q << 6);
      const int rc = (rr < n_e) ? rr : (n_e - 1);
      size_t arow;
      if (MODE == 0) arow = (size_t)lists_tok[e * NTOK + rc] * DIM;
      else           arow = (size_t)(offs[e] + rc) * Hs;
      p[q] = Abase + arow + k0g + off_sh;
    }
    pA0 = p[0]; pA1 = p[1]; pA2 = p[2]; pA3 = p[3];
  }
  // B pointers: rB1 = fold(rw) into {0..31}u{64..95}; B-lo rows rB1+{0,128}, B-hi +32
  const int rB1 = (rw & 31) + ((rw >> 5) << 6);
  const unsigned short* pBl0 = Bexp + (size_t)rB1 * K + off_sh;
  const unsigned short* pBl1 = Bexp + (size_t)(rB1 + 128) * K + off_sh;
  const unsigned short* pBh0 = Bexp + (size_t)(rB1 + 32) * K + off_sh;
  const unsigned short* pBh1 = Bexp + (size_t)(rB1 + 160) * K + off_sh;
  // LDS dest bases (shorts), wave-uniform, rows ≡ 0 mod 8
  const int dA0 = (wv << 3) * 64;
  const int RBw = ((wv << 3) & 31) + (((wv << 3) >> 5) << 6);
  const int dB0 = RBw * 64;

  auto ST = [&](const unsigned short* g, unsigned short* l) {
    __builtin_amdgcn_global_load_lds(
        (const __attribute__((address_space(1))) void*)g,
        (__attribute__((address_space(3))) void*)(void*)l, 16, 0, 0);
  };
  const int nt = Kloc >> 6;
  auto STG_Alo = [&](unsigned short* ab, int t) { if (t < nt) { const int kk = t << 6;
      ST(pA0 + kk, ab + dA0); ST(pA2 + kk, ab + 128 * 64 + dA0); } };
  auto STG_Ahi = [&](unsigned short* ab, int t) { if (t < nt) { const int kk = t << 6;
      ST(pA1 + kk, ab + 64 * 64 + dA0); ST(pA3 + kk, ab + 192 * 64 + dA0); } };
  auto STG_Blo = [&](unsigned short* bb, int t) { if (t < nt) { const int kk = t << 6;
      ST(pBl0 + kk, bb + dB0); ST(pBl1 + kk, bb + 128 * 64 + dB0); } };
  auto STG_Bhi = [&](unsigned short* bb, int t) { if (t < nt) { const int kk = t << 6;
      ST(pBh0 + kk, bb + 32 * 64 + dB0); ST(pBh1 + kk, bb + 160 * 64 + dB0); } };

  const int c = lane >> 4;                   // 16B-chunk within 32-col k-slot
  auto LDA8 = [&](const unsigned short* ab, int i, int s) -> short8 {
    const int row = wm + (i << 4) + (lane & 15);
    return *(const short8*)(ab + row * 64 + ((((s << 2) | c) ^ (row & 7)) << 3));
  };
  auto LDB8 = [&](const unsigned short* bb, int j, int s) -> short8 {
    const int row = wn + (j << 4) + (lane & 15);
    return *(const short8*)(bb + row * 64 + ((((s << 2) | c) ^ (row & 7)) << 3));
  };

  floatx4 acc[8][4];
  #pragma unroll
  for (int i = 0; i < 8; ++i)
    #pragma unroll
    for (int j = 0; j < 4; ++j) acc[i][j] = (floatx4){0.f, 0.f, 0.f, 0.f};

  // prologue: tile0 full (8 calls), tile1 partial (6 calls; A-lo(1) comes at 0.ph0)
  STG_Alo(A0, 0); STG_Blo(B0, 0); STG_Ahi(A0, 0); STG_Bhi(B0, 0);
  STG_Blo(B1, 1); STG_Ahi(A1, 1); STG_Bhi(B1, 1);

  for (int u = 0; u < nt; ++u) {
    const int pb = u & 1;
    const unsigned short* ap = pb ? A1 : A0;
    const unsigned short* bp = pb ? B1 : B0;
    unsigned short* aN = pb ? A0 : A1;       // tile u+1 buffer
    unsigned short* aC = pb ? A1 : A0;       // tile u+2 buffer (current)
    unsigned short* bC = pb ? B1 : B0;

    short8 bk[2][2], ah[4][2], bh[2][2];

    // ---- ph0: (mLo,nLo). vmcnt(6) -> tile-u staging done (3 newer events in flight).
    if (u + 1 < nt) { asm volatile("s_waitcnt vmcnt(6)" ::: "memory"); }
    else            { asm volatile("s_waitcnt vmcnt(0)" ::: "memory"); }
    __builtin_amdgcn_sched_barrier(0);
    __builtin_amdgcn_s_barrier();            // all waves' tile-u staging now visible
    __builtin_amdgcn_sched_barrier(0);
    STG_Alo(aN, u + 1);
    {
      short8 al[4][2];
      #pragma unroll
      for (int i = 0; i < 4; ++i) { al[i][0] = LDA8(ap, i, 0); al[i][1] = LDA8(ap, i, 1); }
      #pragma unroll
      for (int j = 0; j < 2; ++j) { bk[j][0] = LDB8(bp, j, 0); bk[j][1] = LDB8(bp, j, 1); }
      __builtin_amdgcn_s_setprio(1);
      #pragma unroll
      for (int s = 0; s < 2; ++s)
        #pragma unroll
        for (int i = 0; i < 4; ++i)
          #pragma unroll
          for (int j = 0; j < 2; ++j)
            acc[i][j] = __builtin_amdgcn_mfma_f32_16x16x32_bf16(al[i][s], bk[j][s], acc[i][j], 0, 0, 0);
      __builtin_amdgcn_s_setprio(0);
    }
    __builtin_amdgcn_sched_barrier(0);
    __builtin_amdgcn_s_barrier();
    __builtin_amdgcn_sched_barrier(0);

    // ---- ph1: (mHi,nLo) — read A-hi (keep), reuse bk; stage B-lo(u+2) (freed @ph0 bar)
    STG_Blo(bC, u + 2);
    #pragma unroll
    for (int i = 0; i < 4; ++i) { ah[i][0] = LDA8(ap, i + 4, 0); ah[i][1] = LDA8(ap, i + 4, 1); }
    __builtin_amdgcn_s_setprio(1);
    #pragma unroll
    for (int s = 0; s < 2; ++s)
      #pragma unroll
      for (int i = 0; i < 4; ++i)
        #pragma unroll
        for (int j = 0; j < 2; ++j)
          acc[i + 4][j] = __builtin_amdgcn_mfma_f32_16x16x32_bf16(ah[i][s], bk[j][s], acc[i + 4][j], 0, 0, 0);
    __builtin_amdgcn_s_setprio(0);
    __builtin_amdgcn_sched_barrier(0);
    __builtin_amdgcn_s_barrier();
    __builtin_amdgcn_sched_barrier(0);

    // ---- ph2: (mHi,nHi) — read B-hi (keep), reuse ah; stage A-hi(u+2) (freed @ph1 bar)
    STG_Ahi(aC, u + 2);
    #pragma unroll
    for (int j = 0; j < 2; ++j) { bh[j][0] = LDB8(bp, j + 2, 0); bh[j][1] = LDB8(bp, j + 2, 1); }
    __builtin_amdgcn_s_setprio(1);
    #pragma unroll
    for (int s = 0; s < 2; ++s)
      #pragma unroll
      for (int i = 0; i < 4; ++i)
        #pragma unroll
        for (int j = 0; j < 2; ++j)
          acc[i + 4][j + 2] = __builtin_amdgcn_mfma_f32_16x16x32_bf16(ah[i][s], bh[j][s], acc[i + 4][j + 2], 0, 0, 0);
    __builtin_amdgcn_s_setprio(0);
    __builtin_amdgcn_sched_barrier(0);
    __builtin_amdgcn_s_barrier();
    __builtin_amdgcn_sched_barrier(0);

    // ---- ph3: (mLo,nHi) — re-read A-lo, reuse bh; stage B-hi(u+2) (freed @ph2 bar)
    STG_Bhi(bC, u + 2);
    {
      short8 al[4][2];
      #pragma unroll
      for (int i = 0; i < 4; ++i) { al[i][0] = LDA8(ap, i, 0); al[i][1] = LDA8(ap, i, 1); }
      __builtin_amdgcn_s_setprio(1);
      #pragma unroll
      for (int s = 0; s < 2; ++s)
        #pragma unroll
        for (int i = 0; i < 4; ++i)
          #pragma unroll
          for (int j = 0; j < 2; ++j)
            acc[i][j + 2] = __builtin_amdgcn_mfma_f32_16x16x32_bf16(al[i][s], bh[j][s], acc[i][j + 2], 0, 0, 0);
      __builtin_amdgcn_s_setprio(0);
    }
    __builtin_amdgcn_sched_barrier(0);
    __builtin_amdgcn_s_barrier();            // A-lo(u) free -> overwritten at (u+1).ph0
    __builtin_amdgcn_sched_barrier(0);
  }

  // epilogue: C/D map col=lane&15, row=(lane>>4)*4+rr (m89-verified)
  const int q4 = (lane >> 4) << 2;
  if (MODE == 0) {
    #pragma unroll
    for (int i = 0; i < 8; ++i) {
      #pragma unroll
      for (int j = 0; j < 4; ++j) {
        const int nloc = wn + (j << 4) + (lane & 15);
        const float bb = bias[e * HID + hb + nb + nloc];
        #pragma unroll
        for (int rr = 0; rr < 4; ++rr) {
          const int m = m0 + wm + (i << 4) + q4 + rr;
          if (m < n_e) {
            float v = acc[i][j][rr] + bb;
            v = v / (1.0f + __expf(-v));                 // silu
            hout[(size_t)(offs[e] + m) * Hs + nb + nloc] = f2bf(v);
          }
        }
      }
    }
  } else {
    #pragma unroll
    for (int i = 0; i < 8; ++i) {
      #pragma unroll
      for (int rr = 0; rr < 4; ++rr) {
        const int m = m0 + wm + (i << 4) + q4 + rr;
        if (m < n_e) {
          const int   tok = lists_tok[e * NTOK + m];
          const float pp  = lists_p[e * NTOK + m];
          #pragma unroll
          for (int j = 0; j < 4; ++j) {
            const int d = nb + wn + (j << 4) + (lane & 15);
            float v = acc[i][j][rr];
            if (hb == 0 && k0g == 0) v += bias[e * DIM + d];   // add b2 exactly once
            atomicAdd(out + (size_t)tok * DIM + d, pp * v);
          }
        }
      }
    }
  }
}

extern "C" void kernel_launch(void* const* d_in, const int* in_sizes, int n_in,
                              void* d_out, int out_size, void* d_ws, size_t ws_size,
                              hipStream_t stream)
{
  const float* x      = (const float*)d_in[0];
  const float* gate_w = (const float*)d_in[1];
  const float* gate_b = (const float*)d_in[2];
  const float* w1     = (const float*)d_in[3];
  const float* b1     = (const float*)d_in[4];
  const float* w2     = (const float*)d_in[5];
  const float* b2     = (const float*)d_in[6];
  const float* noise  = (const float*)d_in[7];
  float* out = (float*)d_out;

  char* ws = (char*)d_ws;
  const size_t CNT_OFF = 0;          // int counts[8]
  const size_t OFF_OFF = 64;         // int offs[9]
  const size_t NBK_OFF = 128;        // int nblk[1]
  const size_t TBE_OFF = 192;        // int tbl_e[72]
  const size_t TBM_OFF = 1024;       // int tbl_m[72]
  const size_t LT_OFF  = 2048;       // int  lists_tok[8][8192]   (256 KB)
  const size_t LP_OFF  = LT_OFF + 262144;
  const size_t PA_OFF  = LP_OFF + 262144;
  const size_t XB_OFF  = 1048576;    // bf16 xb[8192][1024]       (16 MB)
  const size_t W_OFF   = 17825792;   // bf16 weight-slice buffer  (32 MB / nsl), then h

  // pick H-slicing: need = W_OFF + 32MB/nsl (wt) + 64MB/nsl (h); Hs >= 256 required
  int nsl = 0;
  for (int cand = 1; cand <= 8; cand <<= 1) {
    const size_t need = W_OFF + (size_t)(33554432 + 67108864) / (size_t)cand;
    if (ws_size >= need) { nsl = cand; break; }
  }
  if (!nsl) return;
  const int Hs = HID / nsl;

  int* counts          = (int*)(ws + CNT_OFF);
  int* offs            = (int*)(ws + OFF_OFF);
  int* nblk            = (int*)(ws + NBK_OFF);
  int* tbl_e           = (int*)(ws + TBE_OFF);
  int* tbl_m           = (int*)(ws + TBM_OFF);
  int* lists_tok       = (int*)(ws + LT_OFF);
  float* lists_p       = (float*)(ws + LP_OFF);
  float* probs_all     = (float*)(ws + PA_OFF);
  unsigned short* xb   = (unsigned short*)(ws + XB_OFF);
  unsigned short* wt   = (unsigned short*)(ws + W_OFF);
  unsigned short* hbuf = (unsigned short*)(ws + W_OFF + (size_t)33554432 / nsl);

  hipMemsetAsync(d_out, 0, (size_t)OUT_MAIN * sizeof(float), stream);
  hipMemsetAsync(ws + CNT_OFF, 0, 64, stream);

  k_gating<<<NTOK / 16, 1024, 0, stream>>>(x, gate_w, gate_b, noise, out, counts,
                                           lists_tok, lists_p, probs_all, xb);
  k_offs<<<1, 64, 0, stream>>>(counts, offs, tbl_e, tbl_m, nblk);
  k_aux<<<1, 256, 0, stream>>>(probs_all, out);

  for (int s = 0; s < nsl; ++s) {
    const int hb = s * Hs;
    // w1t slice: w1[e][d][h], rows d (1024), cols h in [hb,hb+Hs) -> wt[e][h'][d]
    dim3 gt1(DIM / 64, Hs / 64, NEXP);
    k_tr<<<gt1, 256, 0, stream>>>(w1, wt, HID, (size_t)DIM * HID, 0, hb,
                                  DIM, (size_t)Hs * DIM);
    dim3 g1(MAXBLK, Hs / 256, 1);
    k_gemm<0><<<g1, 512, 0, stream>>>(xb, wt, b1, counts, offs, tbl_e, tbl_m, nblk,
                                      lists_tok, lists_p, hbuf, out, hb, Hs);
    // w2t slice: w2[e][h][d], rows h in [hb,hb+Hs), cols d (1024) -> wt[e][d][h']
    dim3 gt2(Hs / 64, DIM / 64, NEXP);
    k_tr<<<gt2, 256, 0, stream>>>(w2, wt, DIM, (size_t)DIM * HID, hb, 0,
                                  Hs, (size_t)DIM * Hs);
    dim3 g2(MAXBLK, (DIM / 256) * 2, 1);   // x2 = split-K
    k_gemm<1><<<g2, 512, 0, stream>>>(hbuf, wt, b2, counts, offs, tbl_e, tbl_m, nblk,
                                      lists_tok, lists_p, hbuf, out, hb, Hs);
  }
}

// Round 8
// 420.588 us; speedup vs baseline: 1.1802x; 1.1112x over previous
//
#include <hip/hip_runtime.h>
#include <stdint.h>

// SparseMoE: B=4,S=2048,D=1024,E=8,H=2048, top-k=2.
// Outputs (concat, float32): final_output[8192*1024], top_k_indices[8192*2] (as floats), aux_loss[1].

#define NTOK   8192
#define DIM    1024
#define NEXP   8
#define HID    2048
#define OUT_MAIN (NTOK * DIM)          // 8388608
#define IDX_OFF  OUT_MAIN
#define AUX_OFF  (OUT_MAIN + NTOK * 2) // 8404992
#define MAXBLK 72                      // >= 64 + 7 worst-case 256-row m-blocks over 8 experts

typedef __attribute__((ext_vector_type(8))) short short8;
typedef __attribute__((ext_vector_type(4))) float floatx4;

__device__ __forceinline__ unsigned short f2bf(float f) {
  unsigned int b = __float_as_uint(f);
  b += 0x7FFFu + ((b >> 16) & 1u);      // RNE; inputs finite
  return (unsigned short)(b >> 16);
}

// ---------------- gating: logits (fp64 acc), top-2, masked softmax, list scatter --------
// 1024 threads = 16 waves = 16 tokens/block. No x conversion here (k_gather does it).
__global__ __launch_bounds__(1024) void k_gating(
    const float* __restrict__ x, const float* __restrict__ gate_w,
    const float* __restrict__ gate_b, const float* __restrict__ noise,
    float* __restrict__ out, int* __restrict__ counts,
    int* __restrict__ lists_tok, float* __restrict__ lists_p,
    float* __restrict__ probs_all)
{
  const int lane = threadIdx.x & 63;
  const int wv   = threadIdx.x >> 6;              // 0..15
  const int t    = blockIdx.x * 16 + wv;          // one token per wave
  const float* xr = x + (size_t)t * DIM;

  __shared__ int   cnt[NEXP];
  __shared__ int   base[NEXP];
  __shared__ int   s_e[32];
  __shared__ int   s_pos[32];
  __shared__ float s_p[32];
  if (threadIdx.x < NEXP) cnt[threadIdx.x] = 0;

  double acc[NEXP] = {0,0,0,0,0,0,0,0};
  #pragma unroll
  for (int jj = 0; jj < 4; ++jj) {
    const int d0 = lane * 4 + jj * 256;
    const float4 xv = *(const float4*)(xr + d0);
    const float xs[4] = {xv.x, xv.y, xv.z, xv.w};
    #pragma unroll
    for (int c = 0; c < 4; ++c) {
      const float4 g0 = *(const float4*)(gate_w + (size_t)(d0 + c) * NEXP);
      const float4 g1 = *(const float4*)(gate_w + (size_t)(d0 + c) * NEXP + 4);
      const double xd = (double)xs[c];
      acc[0] += xd * (double)g0.x; acc[1] += xd * (double)g0.y;
      acc[2] += xd * (double)g0.z; acc[3] += xd * (double)g0.w;
      acc[4] += xd * (double)g1.x; acc[5] += xd * (double)g1.y;
      acc[6] += xd * (double)g1.z; acc[7] += xd * (double)g1.w;
    }
  }
  #pragma unroll
  for (int e = 0; e < NEXP; ++e) {
    #pragma unroll
    for (int off = 32; off; off >>= 1) acc[e] += __shfl_xor(acc[e], off);
  }
  __syncthreads();                                 // cnt[] initialized
  if (lane == 0) {
    double l[NEXP];
    #pragma unroll
    for (int e = 0; e < NEXP; ++e)
      l[e] = acc[e] + (double)gate_b[e] + 0.01 * (double)noise[(size_t)t * NEXP + e];
    // top-2 with jax.lax.top_k tie semantics (stable desc: earliest index wins)
    int i1 = 0; double v1 = l[0];
    #pragma unroll
    for (int e = 1; e < NEXP; ++e) if (l[e] > v1) { v1 = l[e]; i1 = e; }
    int i2 = (i1 == 0) ? 1 : 0; double v2 = l[i2];
    #pragma unroll
    for (int e = 0; e < NEXP; ++e) if (e != i1 && l[e] > v2) { v2 = l[e]; i2 = e; }
    float pr[NEXP]; float Z = 0.f;
    #pragma unroll
    for (int e = 0; e < NEXP; ++e) {
      const float a = (l[e] >= v2) ? (float)(l[e] - v1) : -1.0e9f;
      pr[e] = __expf(a); Z += pr[e];
    }
    const float rz = 1.0f / Z;
    #pragma unroll
    for (int e = 0; e < NEXP; ++e) {
      pr[e] *= rz;
      probs_all[(size_t)t * NEXP + e] = pr[e];
    }
    out[(size_t)IDX_OFF + t * 2]     = (float)i1;
    out[(size_t)IDX_OFF + t * 2 + 1] = (float)i2;
    const int p1 = atomicAdd(&cnt[i1], 1);
    const int p2 = atomicAdd(&cnt[i2], 1);
    s_e[wv * 2]     = i1; s_pos[wv * 2]     = p1; s_p[wv * 2]     = pr[i1];
    s_e[wv * 2 + 1] = i2; s_pos[wv * 2 + 1] = p2; s_p[wv * 2 + 1] = pr[i2];
  }
  __syncthreads();
  if (threadIdx.x < NEXP) base[threadIdx.x] = atomicAdd(&counts[threadIdx.x], cnt[threadIdx.x]);
  __syncthreads();
  if (lane == 0) {
    #pragma unroll
    for (int k = 0; k < 2; ++k) {
      const int ee  = s_e[wv * 2 + k];
      const int pos = base[ee] + s_pos[wv * 2 + k];
      lists_tok[ee * NTOK + pos] = t;
      lists_p[ee * NTOK + pos]   = s_p[wv * 2 + k];
    }
  }
}

// ---------------- meta: offsets + balanced XCD-local table (thread 0) + aux loss (all) --
// Table: HW assigns XCD = linear_block_id % 8; gridDim.x=72 (≡0 mod 8) -> XCD = bx%8.
// XCD class c = pos%8 gets a CONTIGUOUS run of valid entries (r3-verified balance+locality).
__global__ __launch_bounds__(256) void k_meta(
    const int* __restrict__ counts, int* __restrict__ offs,
    int* __restrict__ tbl_e, int* __restrict__ tbl_m, int* __restrict__ nblk,
    const float* __restrict__ probs_all, float* __restrict__ out)
{
  if (threadIdx.x == 0) {
    int a = 0;
    #pragma unroll
    for (int e = 0; e < NEXP; ++e) { offs[e] = a; a += counts[e]; }
    offs[NEXP] = a;
    int ent_e[MAXBLK], ent_m[MAXBLK];
    int nb = 0;
    for (int e = 0; e < NEXP; ++e) {
      const int nbe = (counts[e] + 255) >> 8;
      for (int m = 0; m < nbe; ++m) { ent_e[nb] = e; ent_m[nb] = m << 8; ++nb; }
    }
    nblk[0] = nb;
    for (int p = 0; p < MAXBLK; ++p) { tbl_e[p] = -1; tbl_m[p] = 0; }
    const int q = nb >> 3, r = nb & 7;
    for (int c = 0; c < 8; ++c) {
      const int cc    = q + (c < r ? 1 : 0);          // <= 9
      const int start = c * q + (c < r ? c : r);
      for (int t = 0; t < cc; ++t) {
        const int pos = c + (t << 3);                 // pos%8 == c, pos < 72
        tbl_e[pos] = ent_e[start + t];
        tbl_m[pos] = ent_m[start + t];
      }
    }
  }
  // aux loss (all 256 threads)
  float p[NEXP] = {0,0,0,0,0,0,0,0};
  for (int t = threadIdx.x; t < NTOK; t += 256) {
    const float4 a = *(const float4*)(probs_all + (size_t)t * NEXP);
    const float4 b = *(const float4*)(probs_all + (size_t)t * NEXP + 4);
    p[0] += a.x; p[1] += a.y; p[2] += a.z; p[3] += a.w;
    p[4] += b.x; p[5] += b.y; p[6] += b.z; p[7] += b.w;
  }
  #pragma unroll
  for (int e = 0; e < NEXP; ++e) {
    #pragma unroll
    for (int off = 32; off; off >>= 1) p[e] += __shfl_xor(p[e], off);
  }
  __shared__ float red[4][NEXP];
  const int lane = threadIdx.x & 63, wv = threadIdx.x >> 6;
  if (lane == 0) {
    #pragma unroll
    for (int e = 0; e < NEXP; ++e) red[wv][e] = p[e];
  }
  __syncthreads();
  if (threadIdx.x == 0) {
    float usage[NEXP], s = 0.f;
    #pragma unroll
    for (int e = 0; e < NEXP; ++e) {
      usage[e] = red[0][e] + red[1][e] + red[2][e] + red[3][e];
      s += usage[e];
    }
    float imp[NEXP], mean = 0.f, var = 0.f;
    #pragma unroll
    for (int e = 0; e < NEXP; ++e) { imp[e] = usage[e] / s; mean += imp[e]; }
    mean *= 0.125f;
    #pragma unroll
    for (int e = 0; e < NEXP; ++e) { const float d = imp[e] - mean; var += d * d; }
    var *= 0.125f;
    out[AUX_OFF] = sqrtf(var) / (mean + 1e-10f);
  }
}

// ---------------- gather: xg[slot][1024] = bf16(x[lists_tok[slot]])  (slot-contiguous) --
// 4 waves/block, one slot-row per wave; total slots = 16384 exactly (top-2 of 8192).
__global__ __launch_bounds__(256) void k_gather(
    const float* __restrict__ x, const int* __restrict__ offs,
    const int* __restrict__ lists_tok, unsigned short* __restrict__ xg)
{
  const int lane = threadIdx.x & 63;
  const int wv   = threadIdx.x >> 6;
  const int s    = blockIdx.x * 4 + wv;           // 0..16383
  // slot -> expert (linear scan over 8 offsets)
  int e = 0;
  #pragma unroll
  for (int i = 1; i < NEXP; ++i) e += (s >= offs[i]) ? 1 : 0;
  const int tok = lists_tok[e * NTOK + (s - offs[e])];
  const float* xr = x + (size_t)tok * DIM;
  unsigned short* dst = xg + (size_t)s * DIM;
  #pragma unroll
  for (int it = 0; it < 4; ++it) {
    const int d0 = lane * 4 + it * 256;
    const float4 v = *(const float4*)(xr + d0);
    ushort4 q;
    q.x = f2bf(v.x); q.y = f2bf(v.y); q.z = f2bf(v.z); q.w = f2bf(v.w);
    *(ushort4*)(dst + d0) = q;
  }
}

// ---------------- weight transpose+convert: in[e][r][c] fp32 -> out[e][c-c0][r-r0] bf16 ---
__global__ __launch_bounds__(256) void k_tr(
    const float* __restrict__ in, unsigned short* __restrict__ out,
    int in_ld, size_t in_estride, int r0, int c0,
    int out_ld, size_t out_estride)
{
  const int e  = blockIdx.z;
  const int tr = blockIdx.x << 6;
  const int tc = blockIdx.y << 6;
  const int tid = threadIdx.x;
  __shared__ float t[64][65];
  const float* src = in + (size_t)e * in_estride + (size_t)(r0 + tr) * in_ld + (c0 + tc);
  #pragma unroll
  for (int p = 0; p < 4; ++p) {
    const int r  = (p << 4) + (tid >> 4);
    const int c4 = (tid & 15) << 2;
    const float4 v = *(const float4*)(src + (size_t)r * in_ld + c4);
    t[r][c4] = v.x; t[r][c4 + 1] = v.y; t[r][c4 + 2] = v.z; t[r][c4 + 3] = v.w;
  }
  __syncthreads();
  unsigned short* dst = out + (size_t)e * out_estride + (size_t)tc * out_ld + tr;
  #pragma unroll
  for (int p = 0; p < 4; ++p) {
    const int c  = (p << 4) + (tid >> 4);
    const int r4 = (tid & 15) << 2;
    ushort4 q;
    q.x = f2bf(t[r4][c]);     q.y = f2bf(t[r4 + 1][c]);
    q.z = f2bf(t[r4 + 2][c]); q.w = f2bf(t[r4 + 3][c]);
    *(ushort4*)(dst + (size_t)c * out_ld + r4) = q;
  }
}

// ---------------- grouped MFMA GEMM: 256x256 tile, 16 waves, BK=64, counted-vmcnt pipe --
// EXACT r3-verified loop (175 us/GEMM): double-buffered 128 KB LDS, 4 gload_lds per wave
// per K-tile, prologue primes 2 tiles, loop waits vmcnt(4) so tile t+1 stays in flight
// ACROSS the barrier (never vmcnt(0) mid-loop), raw s_barrier + sched_barrier(0) fences,
// setprio(1) MFMA clusters. Tile t+2 issued after the trailing barrier (WAR-safe).
// CHANGE vs r3: MODE 0 A is now DENSE slot-ordered xg (no lists_tok indirection) —
// ablates the gathered-A penalty; MODE 1 untouched (control).
// MODE 0: h[slot, nb+n] = silu( xg[slot] @ w1t[e][nb+n][:] + b1 )   (K = 1024)
// MODE 1 (split-K=2): out[tok, nb+n] += p * ( h[slot] @ w2t[e][nb+n][:] + b2 )
// LDS [row][64] 16B-chunk XOR swizzle (r3-verified, conflicts=0): LDS[r][j]=glob[r][j^(r&7)].
template <int MODE>
__global__ __launch_bounds__(1024) void k_gemm(
    const unsigned short* __restrict__ Abase,
    const unsigned short* __restrict__ Bt,
    const float* __restrict__ bias,
    const int* __restrict__ counts, const int* __restrict__ offs,
    const int* __restrict__ tbl_e, const int* __restrict__ tbl_m,
    const int* __restrict__ nblk,
    const int* __restrict__ lists_tok, const float* __restrict__ lists_p,
    unsigned short* __restrict__ hout, float* __restrict__ out,
    const int hb, const int Hs)
{
  const int bx = blockIdx.x;
  const int e  = tbl_e[bx];
  if (e < 0) return;
  const int m0  = tbl_m[bx];
  const int n_e = counts[e];
  const int by  = blockIdx.y;

  int nb, k0g, Kloc;
  if (MODE == 0) { nb = by << 8; k0g = 0; Kloc = DIM; }
  else { nb = (by >> 1) << 8; const int half = Hs >> 1;
         k0g = (by & 1) * half; Kloc = half; }

  const int tid  = threadIdx.x;
  const int lane = tid & 63;
  const int wv   = tid >> 6;                 // 0..15
  const int wm   = (wv & 3) << 6;
  const int wn   = (wv >> 2) << 6;

  __shared__ __align__(16) unsigned short as[2][256 * 64];  // 2 x 32 KB
  __shared__ __align__(16) unsigned short bs[2][256 * 64];  // 2 x 32 KB

  const int K = (MODE == 0) ? DIM : Hs;      // row stride of both A and B
  const unsigned short* Bexp = Bt + (size_t)e * ((size_t)DIM * Hs) + (size_t)nb * K + k0g;

  // staging: 4 gload_lds per wave per K-tile (A rows 0-127 / 128-255, B same).
  // lane l covers row base+(l>>3), chunk l&7; global chunk = (l&7)^(l>>3)
  // -> LDS[r][j] = global[r][j^(r&7)]  (r&7 == l>>3 since base ≡ 0 mod 8).
  const int off_sh = ((lane & 7) ^ (lane >> 3)) << 3;   // shorts within row
  const int Ra0 = wv * 8 + (lane >> 3);                 // 0..127
  const int Ra1 = 128 + Ra0;                            // 128..255
  const int rc0 = (m0 + Ra0 < n_e) ? (m0 + Ra0) : (n_e - 1);
  const int rc1 = (m0 + Ra1 < n_e) ? (m0 + Ra1) : (n_e - 1);
  // DENSE slot-ordered A for both modes: row (offs[e]+rc) with stride K
  const size_t arow0 = (size_t)(offs[e] + rc0) * K;
  const size_t arow1 = (size_t)(offs[e] + rc1) * K;
  const unsigned short* gpa0 = Abase + arow0 + k0g + off_sh;
  const unsigned short* gpa1 = Abase + arow1 + k0g + off_sh;
  const unsigned short* gpb0 = Bexp + (size_t)Ra0 * K + off_sh;
  const unsigned short* gpb1 = Bexp + (size_t)Ra1 * K + off_sh;

  floatx4 acc[4][4];
  #pragma unroll
  for (int i = 0; i < 4; ++i)
    #pragma unroll
    for (int j2 = 0; j2 < 4; ++j2) acc[i][j2] = (floatx4){0.f, 0.f, 0.f, 0.f};

  auto issue = [&](int buf, int kk) {
    unsigned short* a0 = (buf ? &as[1][0] : &as[0][0]) + wv * 8 * 64;
    unsigned short* b0 = (buf ? &bs[1][0] : &bs[0][0]) + wv * 8 * 64;
    __builtin_amdgcn_global_load_lds(
        (const __attribute__((address_space(1))) void*)(gpa0 + kk),
        (__attribute__((address_space(3))) void*)(void*)a0, 16, 0, 0);
    __builtin_amdgcn_global_load_lds(
        (const __attribute__((address_space(1))) void*)(gpa1 + kk),
        (__attribute__((address_space(3))) void*)(void*)(a0 + 128 * 64), 16, 0, 0);
    __builtin_amdgcn_global_load_lds(
        (const __attribute__((address_space(1))) void*)(gpb0 + kk),
        (__attribute__((address_space(3))) void*)(void*)b0, 16, 0, 0);
    __builtin_amdgcn_global_load_lds(
        (const __attribute__((address_space(1))) void*)(gpb1 + kk),
        (__attribute__((address_space(3))) void*)(void*)(b0 + 128 * 64), 16, 0, 0);
  };

  const int nt = Kloc >> 6;                  // K-tiles of 64 (>= 2 for all Hs >= 256)
  issue(0, 0);
  issue(1, 64);
  int p = 0;
  for (int t = 0; t < nt; ++t) {
    // tile t complete; tile t+1's 4 calls stay in flight across the barrier (T4)
    if (t + 1 < nt) { asm volatile("s_waitcnt vmcnt(4)" ::: "memory"); }
    else            { asm volatile("s_waitcnt vmcnt(0)" ::: "memory"); }
    __builtin_amdgcn_sched_barrier(0);
    __builtin_amdgcn_s_barrier();
    __builtin_amdgcn_sched_barrier(0);
    const unsigned short* ap = p ? &as[1][0] : &as[0][0];
    const unsigned short* bp = p ? &bs[1][0] : &bs[0][0];
    const int c = lane >> 4;                 // 16B-chunk within 32-col k-slot
    #pragma unroll
    for (int s = 0; s < 2; ++s) {            // two k-slots of 32 per K-tile
      short8 af[4], bfr[4];
      #pragma unroll
      for (int i = 0; i < 4; ++i) {
        const int row = wm + (i << 4) + (lane & 15);
        af[i] = *(const short8*)(ap + row * 64 + ((((s << 2) | c) ^ (row & 7)) << 3));
      }
      #pragma unroll
      for (int j2 = 0; j2 < 4; ++j2) {
        const int row = wn + (j2 << 4) + (lane & 15);
        bfr[j2] = *(const short8*)(bp + row * 64 + ((((s << 2) | c) ^ (row & 7)) << 3));
      }
      __builtin_amdgcn_s_setprio(1);
      #pragma unroll
      for (int i = 0; i < 4; ++i)
        #pragma unroll
        for (int j2 = 0; j2 < 4; ++j2)
          acc[i][j2] = __builtin_amdgcn_mfma_f32_16x16x32_bf16(af[i], bfr[j2], acc[i][j2], 0, 0, 0);
      __builtin_amdgcn_s_setprio(0);
    }
    __builtin_amdgcn_sched_barrier(0);
    __builtin_amdgcn_s_barrier();            // all waves done reading buf p
    __builtin_amdgcn_sched_barrier(0);
    if (t + 2 < nt) issue(p, (t + 2) << 6);  // overwrite tile t's buffer (safe)
    p ^= 1;
  }

  // epilogue: C/D map col=lane&15, row=(lane>>4)*4+rr (m89-verified)
  const int q4 = (lane >> 4) << 2;
  if (MODE == 0) {
    #pragma unroll
    for (int i = 0; i < 4; ++i) {
      #pragma unroll
      for (int j2 = 0; j2 < 4; ++j2) {
        const int nloc = wn + (j2 << 4) + (lane & 15);
        const float bb = bias[e * HID + hb + nb + nloc];
        #pragma unroll
        for (int rr = 0; rr < 4; ++rr) {
          const int m = m0 + wm + (i << 4) + q4 + rr;
          if (m < n_e) {
            float v = acc[i][j2][rr] + bb;
            v = v / (1.0f + __expf(-v));                 // silu
            hout[(size_t)(offs[e] + m) * Hs + nb + nloc] = f2bf(v);
          }
        }
      }
    }
  } else {
    #pragma unroll
    for (int i = 0; i < 4; ++i) {
      #pragma unroll
      for (int rr = 0; rr < 4; ++rr) {
        const int m = m0 + wm + (i << 4) + q4 + rr;
        if (m < n_e) {
          const int   tok = lists_tok[e * NTOK + m];
          const float pp  = lists_p[e * NTOK + m];
          #pragma unroll
          for (int j2 = 0; j2 < 4; ++j2) {
            const int d = nb + wn + (j2 << 4) + (lane & 15);
            float v = acc[i][j2][rr];
            if (hb == 0 && k0g == 0) v += bias[e * DIM + d];   // add b2 exactly once
            atomicAdd(out + (size_t)tok * DIM + d, pp * v);
          }
        }
      }
    }
  }
}

extern "C" void kernel_launch(void* const* d_in, const int* in_sizes, int n_in,
                              void* d_out, int out_size, void* d_ws, size_t ws_size,
                              hipStream_t stream)
{
  const float* x      = (const float*)d_in[0];
  const float* gate_w = (const float*)d_in[1];
  const float* gate_b = (const float*)d_in[2];
  const float* w1     = (const float*)d_in[3];
  const float* b1     = (const float*)d_in[4];
  const float* w2     = (const float*)d_in[5];
  const float* b2     = (const float*)d_in[6];
  const float* noise  = (const float*)d_in[7];
  float* out = (float*)d_out;

  char* ws = (char*)d_ws;
  const size_t CNT_OFF = 0;          // int counts[8]
  const size_t OFF_OFF = 64;         // int offs[9]
  const size_t NBK_OFF = 128;        // int nblk[1]
  const size_t TBE_OFF = 192;        // int tbl_e[72]
  const size_t TBM_OFF = 1024;       // int tbl_m[72]
  const size_t LT_OFF  = 2048;       // int  lists_tok[8][8192]   (256 KB)
  const size_t LP_OFF  = LT_OFF + 262144;
  const size_t PA_OFF  = LP_OFF + 262144;
  const size_t XG_OFF  = 1048576;    // bf16 xg[16384][1024]      (32 MB, slot-ordered)
  const size_t W_OFF   = XG_OFF + 33554432;   // 34603008: wt (32MB/nsl) then h (64MB/nsl)

  // pick H-slicing: need = W_OFF + 32MB/nsl (wt) + 64MB/nsl (h); Hs >= 256 required
  int nsl = 0;
  for (int cand = 1; cand <= 8; cand <<= 1) {
    const size_t need = W_OFF + (size_t)(33554432 + 67108864) / (size_t)cand;
    if (ws_size >= need) { nsl = cand; break; }
  }
  if (!nsl) return;
  const int Hs = HID / nsl;

  int* counts          = (int*)(ws + CNT_OFF);
  int* offs            = (int*)(ws + OFF_OFF);
  int* nblk            = (int*)(ws + NBK_OFF);
  int* tbl_e           = (int*)(ws + TBE_OFF);
  int* tbl_m           = (int*)(ws + TBM_OFF);
  int* lists_tok       = (int*)(ws + LT_OFF);
  float* lists_p       = (float*)(ws + LP_OFF);
  float* probs_all     = (float*)(ws + PA_OFF);
  unsigned short* xg   = (unsigned short*)(ws + XG_OFF);
  unsigned short* wt   = (unsigned short*)(ws + W_OFF);
  unsigned short* hbuf = (unsigned short*)(ws + W_OFF + (size_t)33554432 / nsl);

  hipMemsetAsync(d_out, 0, (size_t)OUT_MAIN * sizeof(float), stream);
  hipMemsetAsync(ws + CNT_OFF, 0, 64, stream);

  k_gating<<<NTOK / 16, 1024, 0, stream>>>(x, gate_w, gate_b, noise, out, counts,
                                           lists_tok, lists_p, probs_all);
  k_meta<<<1, 256, 0, stream>>>(counts, offs, tbl_e, tbl_m, nblk, probs_all, out);
  k_gather<<<16384 / 4, 256, 0, stream>>>(x, offs, lists_tok, xg);

  for (int s = 0; s < nsl; ++s) {
    const int hb = s * Hs;
    // w1t slice: w1[e][d][h], rows d (1024), cols h in [hb,hb+Hs) -> wt[e][h'][d]
    dim3 gt1(DIM / 64, Hs / 64, NEXP);
    k_tr<<<gt1, 256, 0, stream>>>(w1, wt, HID, (size_t)DIM * HID, 0, hb,
                                  DIM, (size_t)Hs * DIM);
    dim3 g1(MAXBLK, Hs / 256, 1);
    k_gemm<0><<<g1, 1024, 0, stream>>>(xg, wt, b1, counts, offs, tbl_e, tbl_m, nblk,
                                       lists_tok, lists_p, hbuf, out, hb, Hs);
    // w2t slice: w2[e][h][d], rows h in [hb,hb+Hs), cols d (1024) -> wt[e][d][h']
    dim3 gt2(Hs / 64, DIM / 64, NEXP);
    k_tr<<<gt2, 256, 0, stream>>>(w2, wt, DIM, (size_t)DIM * HID, hb, 0,
                                  Hs, (size_t)DIM * Hs);
    dim3 g2(MAXBLK, (DIM / 256) * 2, 1);   // x2 = split-K
    k_gemm<1><<<g2, 1024, 0, stream>>>(hbuf, wt, b2, counts, offs, tbl_e, tbl_m, nblk,
                                       lists_tok, lists_p, hbuf, out, hb, Hs);
  }
}